// Round 10
// baseline (315.996 us; speedup 1.0000x reference)
//
#include <hip/hip_runtime.h>
#include <hip/hip_bf16.h>

// Problem constants
#define B_  2
#define N_  2048
#define D_  1024
#define H_  16
#define DH_ 64
#define BN_ (B_*N_)   // 4096 rows total

typedef __attribute__((ext_vector_type(8))) short short8;    // 8 bf16 (K=16/32 A/B frag)
typedef __attribute__((ext_vector_type(4))) float f32x4;     // 16x16 C/D frag
typedef __attribute__((ext_vector_type(16))) float f32x16;   // 32x32 C/D frag
typedef __attribute__((ext_vector_type(4))) unsigned int uint4v;

typedef __attribute__((address_space(3))) unsigned int lds_u32_t;
typedef const __attribute__((address_space(1))) unsigned int glb_u32_t;

// async global->LDS, 16B per lane; LDS dst = (wave-uniform base) + lane*16
__device__ __forceinline__ void async_load16(const unsigned short* g, unsigned short* l) {
    __builtin_amdgcn_global_load_lds((glb_u32_t*)g, (lds_u32_t*)l, 16, 0, 0);
}

__device__ __forceinline__ unsigned short f2bf(float f) {
    __hip_bfloat16 h = __float2bfloat16(f);
    return *reinterpret_cast<unsigned short*>(&h);
}

// pack bf16(a) low16 | bf16(b) high16; round-half-up + one v_perm_b32
__device__ __forceinline__ unsigned int pkbf(float a, float b) {
    unsigned int ua = __float_as_uint(a) + 0x8000u;
    unsigned int ub = __float_as_uint(b) + 0x8000u;
    return __builtin_amdgcn_perm(ub, ua, 0x07060302);
}

#if __has_builtin(__builtin_amdgcn_exp2f)
#define EXP2(x) __builtin_amdgcn_exp2f(x)
#else
#define EXP2(x) exp2f(x)
#endif

// softmax scale folded into Q projection: 1/sqrt(DH) * log2(e)
#define QSCL 0.1803368801111204f

// ---------------------------------------------------------------------------
// Kernel 1: cast fp32 -> bf16 for x, Wq, Wk, Wv, Wo (one fused launch)
// ---------------------------------------------------------------------------
__global__ __launch_bounds__(256) void cast_kernel(
    const float* __restrict__ x,  const float* __restrict__ wq,
    const float* __restrict__ wk, const float* __restrict__ wv,
    const float* __restrict__ wo,
    unsigned short* __restrict__ xb,  unsigned short* __restrict__ wqb,
    unsigned short* __restrict__ wkb, unsigned short* __restrict__ wvb,
    unsigned short* __restrict__ wob)
{
    const size_t NX = (size_t)BN_ * D_;   // 4194304
    const size_t NW = (size_t)D_ * D_;    // 1048576 (pow2)
    size_t i = ((size_t)blockIdx.x * 256 + threadIdx.x) * 4;
    const float* src; unsigned short* dst; size_t off;
    if (i < NX) { src = x; dst = xb; off = i; }
    else {
        size_t j = (i - NX) >> 20;          // which W
        off = (i - NX) & (NW - 1);
        src = (j == 0) ? wq : (j == 1) ? wk : (j == 2) ? wv : wo;
        dst = (j == 0) ? wqb : (j == 1) ? wkb : (j == 2) ? wvb : wob;
    }
    float4 v = *(const float4*)(src + off);
    ushort4 o;
    o.x = f2bf(v.x); o.y = f2bf(v.y); o.z = f2bf(v.z); o.w = f2bf(v.w);
    *(ushort4*)(dst + off) = o;
}

// ---------------------------------------------------------------------------
// GEMM body, R9 shape: 64x128 tile (BM=64), 4 waves x (64x32 acc[4][2]),
// single-buffered 24 KB LDS. UNCHANGED from R9 (measurement round).
// ---------------------------------------------------------------------------
template<int OUT_MODE>
__device__ __forceinline__ void gemm_body(
    unsigned short* __restrict__ As, unsigned short* __restrict__ Bs,
    const unsigned short* __restrict__ A, const unsigned short* __restrict__ W,
    const float* __restrict__ bias, void* __restrict__ Cout, int bx, int by)
{
    constexpr int K = D_;
    const int tid  = threadIdx.x;
    const int lane = tid & 63;
    const int wave = tid >> 6;
    const int l15 = lane & 15, quad = lane >> 4;

    f32x4 acc[4][2] = {};
    const int row0 = by * 64, col0 = bx * 128;

    const int srow = lane >> 3;   // row within 1KB chunk (8 rows x 128B)
    const int scb  = lane & 7;    // 16B block within row

    for (int k0 = 0; k0 < K; k0 += 64) {
        __syncthreads();
        // A tile: 64 rows = 8 chunks; B tile: 128 rows = 16 chunks
#pragma unroll
        for (int cc = 0; cc < 2; ++cc) {
            int c  = wave * 2 + cc;            // 0..7
            int lr = c * 8 + srow;             // A row 0..63
            int gcol = k0 + ((scb ^ (lr & 7)) * 8);
            async_load16(A + (size_t)(row0 + lr) * K + gcol, As + c * 512);
        }
#pragma unroll
        for (int cc = 0; cc < 4; ++cc) {
            int c  = wave * 4 + cc;            // 0..15
            int lr = c * 8 + srow;             // B row (out col) 0..127
            int gcol = k0 + ((scb ^ (lr & 7)) * 8);
            async_load16(W + (size_t)(col0 + lr) * K + gcol, Bs + c * 512);
        }
        __syncthreads();

#pragma unroll
        for (int kf = 0; kf < 2; ++kf) {
            const int swz = ((kf * 4 + quad) ^ (l15 & 7)) * 8;
            short8 af[4], bf[2];
#pragma unroll
            for (int mi = 0; mi < 4; mi++)
                af[mi] = *(const short8*)(&As[(mi * 16 + l15) * 64 + swz]);
#pragma unroll
            for (int ni = 0; ni < 2; ni++)
                bf[ni] = *(const short8*)(&Bs[(wave * 32 + ni * 16 + l15) * 64 + swz]);
#pragma unroll
            for (int mi = 0; mi < 4; mi++)
#pragma unroll
                for (int ni = 0; ni < 2; ni++)
                    acc[mi][ni] = __builtin_amdgcn_mfma_f32_16x16x32_bf16(
                        af[mi], bf[ni], acc[mi][ni], 0, 0, 0);
        }
    }

    if (OUT_MODE == 2) {
        // ---- V^T epilogue: stage 128c x 64r tile in Bs, coalesced write ----
        __syncthreads();   // all waves done reading LDS from the last tile
#pragma unroll
        for (int ni = 0; ni < 2; ni++) {
            int c = wave * 32 + ni * 16 + l15;        // local col 0..127
            float bv = bias[col0 + c];
#pragma unroll
            for (int mi = 0; mi < 4; mi++) {
                int r = mi * 16 + quad * 4;           // local row, multiple of 4
                ushort4 pk;
                pk.x = f2bf(acc[mi][ni][0] + bv);
                pk.y = f2bf(acc[mi][ni][1] + bv);
                pk.z = f2bf(acc[mi][ni][2] + bv);
                pk.w = f2bf(acc[mi][ni][3] + bv);
                *(ushort4*)(Bs + c * 64 + (r ^ ((c & 7) << 3))) = pk;  // XOR swz
            }
        }
        __syncthreads();
        // 1024 items = 128 cols x 8 row-blocks(16B); 8 consecutive lanes share c
#pragma unroll
        for (int itx = 0; itx < 4; ++itx) {
            int item = itx * 256 + tid;
            int c  = item >> 3;        // 0..127
            int rb = item & 7;         // logical 8-elem row block
            uint4v v = *(const uint4v*)(Bs + c * 64 + ((rb ^ (c & 7)) * 8));
            *(uint4v*)((unsigned short*)Cout + (size_t)(col0 + c) * BN_ + row0 + rb * 8) = v;
        }
        return;
    }

#pragma unroll
    for (int ni = 0; ni < 2; ni++) {
        int col = col0 + wave * 32 + ni * 16 + l15;
        float bv = bias[col];
#pragma unroll
        for (int mi = 0; mi < 4; mi++) {
            int row = row0 + mi * 16 + quad * 4;
#pragma unroll
            for (int r = 0; r < 4; r++) {
                float v = acc[mi][ni][r] + bv;
                if (OUT_MODE == 3) v *= QSCL;
                if (OUT_MODE == 0)
                    ((float*)Cout)[(size_t)(row + r) * D_ + col] = v;
                else
                    ((unsigned short*)Cout)[(size_t)(row + r) * D_ + col] = f2bf(v);
            }
        }
    }
}

// XCD-aware bijective block swizzle (T1), nwg = 8x64 = 512 per z-slice.
__device__ __forceinline__ void xcd_swz(int& bx, int& by) {
    int w = blockIdx.y * 8 + blockIdx.x;      // dispatch-flat (x fastest)
    int s = (w & 7) * 64 + (w >> 3);          // bijective, nwg=512
    bx = s & 7; by = s >> 3;
}

// ---------------------------------------------------------------------------
// MEASUREMENT ROUND (R10): qkv_x2 / out_x3 run the identical GEMM body 2x/3x
// (idempotent global writes — results unchanged). Purpose: their dispatch
// durations exceed attn's ~70 us, so they SURFACE IN THE TOP-5 with their own
// MfmaUtil/VALUBusy/Occupancy/VGPR/scratch counters — the first direct GEMM
// evidence of the session. qkv = dur(qkv_x2)/2; out = dur(out_x3)/3; also
// total - R9_total = qkv + 2*out. Reverts to single-rep next round.
// ---------------------------------------------------------------------------
__global__ __launch_bounds__(256, 5) void qkv_x2(
    const unsigned short* __restrict__ xb,
    const unsigned short* __restrict__ wqb, const unsigned short* __restrict__ wkb,
    const unsigned short* __restrict__ wvb,
    const float* __restrict__ bq, const float* __restrict__ bk, const float* __restrict__ bv,
    unsigned short* __restrict__ q, unsigned short* __restrict__ k, unsigned short* __restrict__ vt)
{
    __shared__ __align__(16) unsigned short As[64 * 64];    //  8 KB
    __shared__ __align__(16) unsigned short Bs[128 * 64];   // 16 KB
    int bx, by; xcd_swz(bx, by);
#pragma unroll 1
    for (int rep = 0; rep < 2; ++rep) {
        if (blockIdx.z == 0)
            gemm_body<3>(As, Bs, xb, wqb, bq, q,  bx, by);
        else if (blockIdx.z == 1)
            gemm_body<1>(As, Bs, xb, wkb, bk, k,  bx, by);
        else
            gemm_body<2>(As, Bs, xb, wvb, bv, vt, bx, by);
    }
}

__global__ __launch_bounds__(256, 5) void out_x3(
    const unsigned short* __restrict__ attn, const unsigned short* __restrict__ wob,
    const float* __restrict__ bo, float* __restrict__ out)
{
    __shared__ __align__(16) unsigned short As[64 * 64];
    __shared__ __align__(16) unsigned short Bs[128 * 64];
    int bx, by; xcd_swz(bx, by);
#pragma unroll 1
    for (int rep = 0; rep < 3; ++rep)
        gemm_body<0>(As, Bs, attn, wob, bo, out, bx, by);
}

// ---------------------------------------------------------------------------
// Kernel 3: flash attention — R9 form unchanged (setprio kept).
// ---------------------------------------------------------------------------
__global__ __launch_bounds__(256) void attn_kernel(
    const unsigned short* __restrict__ q, const unsigned short* __restrict__ k,
    const unsigned short* __restrict__ vt, unsigned short* __restrict__ o)
{
    __shared__ __align__(16) unsigned short Ks[2][64 * 64];
    __shared__ __align__(16) unsigned short Vs[2][64 * 64];

    const int tid = threadIdx.x;
    const int lane = tid & 63, wave = tid >> 6;
    const int l31 = lane & 31, kq = lane >> 5;
    const int bh = blockIdx.x;
    const int qt = blockIdx.y;
    const int b = bh >> 4, h = bh & 15;

    const unsigned short* qb = q  + (size_t)b * N_ * D_ + h * DH_;
    const unsigned short* kb = k  + (size_t)b * N_ * D_ + h * DH_;
    const unsigned short* vb = vt + (size_t)h * DH_ * BN_ + (size_t)b * N_;

    const int qrow0 = qt * 128 + wave * 32;

    short8 qf[4];
#pragma unroll
    for (int s = 0; s < 4; s++)
        qf[s] = *(const short8*)(qb + (size_t)(qrow0 + l31) * D_ + s * 16 + kq * 8);

    f32x16 oacc[2] = {};
    float lsum = 0.f;

    const int srow = lane >> 3, scb = lane & 7;

    auto stage = [&](int bi, int kv0) {
#pragma unroll
        for (int cc = 0; cc < 2; ++cc) {
            int c  = wave * 2 + cc;
            int lr = c * 8 + srow;
            int swz8 = (scb ^ (lr & 7)) * 8;
            async_load16(kb + (size_t)(kv0 + lr) * D_ + swz8, (unsigned short*)Ks[bi] + c * 512);
            async_load16(vb + (size_t)lr * BN_ + kv0 + swz8,  (unsigned short*)Vs[bi] + c * 512);
        }
    };

    stage(0, 0);

    const int NIT = N_ / 64;
    for (int it = 0; it < NIT; ++it) {
        const int cur = it & 1;
        __syncthreads();
        if (it + 1 < NIT) stage(cur ^ 1, (it + 1) * 64);

        const unsigned short* Kc = Ks[cur];
        const unsigned short* Vc = Vs[cur];

        f32x16 st[2] = {};
        __builtin_amdgcn_s_setprio(1);
#pragma unroll
        for (int s = 0; s < 4; s++) {
#pragma unroll
            for (int mb = 0; mb < 2; mb++) {
                short8 kfr = *(const short8*)((const char*)Kc +
                    (mb * 32 + l31) * 128 + (((2 * s + kq) ^ (l31 & 7)) * 16));
                st[mb] = __builtin_amdgcn_mfma_f32_32x32x16_bf16(
                    kfr, qf[s], st[mb], 0, 0, 0);
            }
        }
        __builtin_amdgcn_s_setprio(0);

#pragma unroll
        for (int mb = 0; mb < 2; mb++) {
            unsigned int pk[8];
#pragma unroll
            for (int g = 0; g < 4; g++) {
                float p0 = EXP2(st[mb][g * 4 + 0]);
                float p1 = EXP2(st[mb][g * 4 + 1]);
                float p2 = EXP2(st[mb][g * 4 + 2]);
                float p3 = EXP2(st[mb][g * 4 + 3]);
                lsum += (p0 + p1) + (p2 + p3);
                pk[2 * g + 0] = pkbf(p0, p1);
                pk[2 * g + 1] = pkbf(p2, p3);
            }
            __builtin_amdgcn_s_setprio(1);
#pragma unroll
            for (int s = 0; s < 2; s++) {
                uint4v fu;
                fu[0] = pk[4 * s + 0]; fu[1] = pk[4 * s + 1];
                fu[2] = pk[4 * s + 2]; fu[3] = pk[4 * s + 3];
                short8 pf = __builtin_bit_cast(short8, fu);
                const int blkA = 4 * mb + 2 * s;
#pragma unroll
                for (int nb = 0; nb < 2; nb++) {
                    const char* vrow = (const char*)Vc + (nb * 32 + l31) * 128;
                    uint2 vlo = *(const uint2*)(vrow + ((blkA       ^ (l31 & 7)) * 16) + kq * 8);
                    uint2 vhi = *(const uint2*)(vrow + (((blkA + 1) ^ (l31 & 7)) * 16) + kq * 8);
                    uint4v vu; vu[0] = vlo.x; vu[1] = vlo.y; vu[2] = vhi.x; vu[3] = vhi.y;
                    short8 vf = __builtin_bit_cast(short8, vu);
                    oacc[nb] = __builtin_amdgcn_mfma_f32_32x32x16_bf16(
                        pf, vf, oacc[nb], 0, 0, 0);
                }
            }
            __builtin_amdgcn_s_setprio(0);
        }
    }

    lsum += __shfl_xor(lsum, 32);
    __syncthreads();
    float* Lt = (float*)&Ks[0][0] + wave * 32;
    if (kq == 0) Lt[l31] = lsum;
    asm volatile("s_waitcnt lgkmcnt(0)" ::: "memory");

#pragma unroll
    for (int g = 0; g < 4; g++)
#pragma unroll
        for (int rr = 0; rr < 4; rr++) {
            int reg = g * 4 + rr;
            float inv = 1.f / Lt[rr + 8 * g + 4 * kq];
            int row = qrow0 + rr + 8 * g + 4 * kq;
            size_t base = ((size_t)b * N_ + row) * D_ + h * DH_;
#pragma unroll
            for (int nb = 0; nb < 2; nb++)
                o[base + nb * 32 + l31] = f2bf(oacc[nb][reg] * inv);
        }
}

// ---------------------------------------------------------------------------
extern "C" void kernel_launch(void* const* d_in, const int* in_sizes, int n_in,
                              void* d_out, int out_size, void* d_ws, size_t ws_size,
                              hipStream_t stream)
{
    const float* x  = (const float*)d_in[0];
    const float* Wq = (const float*)d_in[1];
    const float* bq = (const float*)d_in[2];
    const float* Wk = (const float*)d_in[3];
    const float* bk = (const float*)d_in[4];
    const float* Wv = (const float*)d_in[5];
    const float* bv = (const float*)d_in[6];
    const float* Wo = (const float*)d_in[7];
    const float* bo = (const float*)d_in[8];
    float* out = (float*)d_out;

    char* ws = (char*)d_ws;
    unsigned short* xb  = (unsigned short*)(ws + 0);         //  8 MB  x bf16
    unsigned short* wqb = (unsigned short*)(ws + 8388608);   //  2 MB
    unsigned short* wkb = (unsigned short*)(ws + 10485760);  //  2 MB
    unsigned short* wvb = (unsigned short*)(ws + 12582912);  //  2 MB
    unsigned short* wob = (unsigned short*)(ws + 14680064);  //  2 MB
    unsigned short* qd  = (unsigned short*)(ws + 16777216);  //  8 MB  Q (pre-scaled)
    unsigned short* kd  = (unsigned short*)(ws + 25165824);  //  8 MB
    unsigned short* vtd = (unsigned short*)(ws + 33554432);  //  8 MB  V^T [D][B*N]
    unsigned short* ad  = (unsigned short*)(ws + 41943040);  //  8 MB  attn out
    // total 48 MB

    cast_kernel<<<8192, 256, 0, stream>>>(x, Wq, Wk, Wv, Wo, xb, wqb, wkb, wvb, wob);
    qkv_x2<<<dim3(8, 64, 3), 256, 0, stream>>>(xb, wqb, wkb, wvb, bq, bk, bv, qd, kd, vtd);
    attn_kernel<<<dim3(32, 16), 256, 0, stream>>>(qd, kd, vtd, ad);
    out_x3<<<dim3(8, 64), 256, 0, stream>>>(ad, wob, bo, out);
}

// Round 11
// 194.852 us; speedup vs baseline: 1.6217x; 1.6217x over previous
//
#include <hip/hip_runtime.h>
#include <hip/hip_bf16.h>

// Problem constants
#define B_  2
#define N_  2048
#define D_  1024
#define H_  16
#define DH_ 64
#define BN_ (B_*N_)   // 4096 rows total

typedef __attribute__((ext_vector_type(8))) short short8;    // 8 bf16 (K=16/32 A/B frag)
typedef __attribute__((ext_vector_type(4))) float f32x4;     // 16x16 C/D frag
typedef __attribute__((ext_vector_type(16))) float f32x16;   // 32x32 C/D frag
typedef __attribute__((ext_vector_type(4))) unsigned int uint4v;

typedef __attribute__((address_space(3))) unsigned int lds_u32_t;
typedef const __attribute__((address_space(1))) unsigned int glb_u32_t;

// async global->LDS, 16B per lane; LDS dst = (wave-uniform base) + lane*16
__device__ __forceinline__ void async_load16(const unsigned short* g, unsigned short* l) {
    __builtin_amdgcn_global_load_lds((glb_u32_t*)g, (lds_u32_t*)l, 16, 0, 0);
}

__device__ __forceinline__ unsigned short f2bf(float f) {
    __hip_bfloat16 h = __float2bfloat16(f);
    return *reinterpret_cast<unsigned short*>(&h);
}

// pack bf16(a) low16 | bf16(b) high16; round-half-up + one v_perm_b32
__device__ __forceinline__ unsigned int pkbf(float a, float b) {
    unsigned int ua = __float_as_uint(a) + 0x8000u;
    unsigned int ub = __float_as_uint(b) + 0x8000u;
    return __builtin_amdgcn_perm(ub, ua, 0x07060302);
}

#if __has_builtin(__builtin_amdgcn_exp2f)
#define EXP2(x) __builtin_amdgcn_exp2f(x)
#else
#define EXP2(x) exp2f(x)
#endif

// softmax scale folded into Q projection: 1/sqrt(DH) * log2(e)
#define QSCL 0.1803368801111204f

// ---------------------------------------------------------------------------
// Kernel 1: cast fp32 -> bf16 for x, Wq, Wk, Wv, Wo (one fused launch)
// ---------------------------------------------------------------------------
__global__ __launch_bounds__(256) void cast_kernel(
    const float* __restrict__ x,  const float* __restrict__ wq,
    const float* __restrict__ wk, const float* __restrict__ wv,
    const float* __restrict__ wo,
    unsigned short* __restrict__ xb,  unsigned short* __restrict__ wqb,
    unsigned short* __restrict__ wkb, unsigned short* __restrict__ wvb,
    unsigned short* __restrict__ wob)
{
    const size_t NX = (size_t)BN_ * D_;   // 4194304
    const size_t NW = (size_t)D_ * D_;    // 1048576 (pow2)
    size_t i = ((size_t)blockIdx.x * 256 + threadIdx.x) * 4;
    const float* src; unsigned short* dst; size_t off;
    if (i < NX) { src = x; dst = xb; off = i; }
    else {
        size_t j = (i - NX) >> 20;          // which W
        off = (i - NX) & (NW - 1);
        src = (j == 0) ? wq : (j == 1) ? wk : (j == 2) ? wv : wo;
        dst = (j == 0) ? wqb : (j == 1) ? wkb : (j == 2) ? wvb : wob;
    }
    float4 v = *(const float4*)(src + off);
    ushort4 o;
    o.x = f2bf(v.x); o.y = f2bf(v.y); o.z = f2bf(v.z); o.w = f2bf(v.w);
    *(ushort4*)(dst + off) = o;
}

// ---------------------------------------------------------------------------
// GEMM body, R11: 64x128 tile, 4 waves x acc[4][2], 24 KB LDS (R9 shape).
// R10 MEASUREMENT: qkv=62us out=29us; qkv counters MfmaUtil 16.5 / VALU 11 /
// Occ 41% but 3.17 TB/s sustained with WRITE_SIZE 5x ideal — Q/K scalar
// 2B stores are the convicted write-amplifier. R11 fix: OUT_MODE 1/3 now
// stage the 64x128 tile in Bs (dead after K-loop, 16 KB exact) with XOR
// swizzle col^((row&7)<<3) (<=2-way banks both sides, same scheme as the
// verified V^T epilogue) and write coalesced 16B runs along D: 16 lanes =
// 256B contiguous per row -> 1x write amplification.
// ---------------------------------------------------------------------------
template<int OUT_MODE>
__device__ __forceinline__ void gemm_body(
    unsigned short* __restrict__ As, unsigned short* __restrict__ Bs,
    const unsigned short* __restrict__ A, const unsigned short* __restrict__ W,
    const float* __restrict__ bias, void* __restrict__ Cout, int bx, int by)
{
    constexpr int K = D_;
    const int tid  = threadIdx.x;
    const int lane = tid & 63;
    const int wave = tid >> 6;
    const int l15 = lane & 15, quad = lane >> 4;

    f32x4 acc[4][2] = {};
    const int row0 = by * 64, col0 = bx * 128;

    const int srow = lane >> 3;   // row within 1KB chunk (8 rows x 128B)
    const int scb  = lane & 7;    // 16B block within row

    for (int k0 = 0; k0 < K; k0 += 64) {
        __syncthreads();
        // A tile: 64 rows = 8 chunks; B tile: 128 rows = 16 chunks
#pragma unroll
        for (int cc = 0; cc < 2; ++cc) {
            int c  = wave * 2 + cc;            // 0..7
            int lr = c * 8 + srow;             // A row 0..63
            int gcol = k0 + ((scb ^ (lr & 7)) * 8);
            async_load16(A + (size_t)(row0 + lr) * K + gcol, As + c * 512);
        }
#pragma unroll
        for (int cc = 0; cc < 4; ++cc) {
            int c  = wave * 4 + cc;            // 0..15
            int lr = c * 8 + srow;             // B row (out col) 0..127
            int gcol = k0 + ((scb ^ (lr & 7)) * 8);
            async_load16(W + (size_t)(col0 + lr) * K + gcol, Bs + c * 512);
        }
        __syncthreads();

#pragma unroll
        for (int kf = 0; kf < 2; ++kf) {
            const int swz = ((kf * 4 + quad) ^ (l15 & 7)) * 8;
            short8 af[4], bf[2];
#pragma unroll
            for (int mi = 0; mi < 4; mi++)
                af[mi] = *(const short8*)(&As[(mi * 16 + l15) * 64 + swz]);
#pragma unroll
            for (int ni = 0; ni < 2; ni++)
                bf[ni] = *(const short8*)(&Bs[(wave * 32 + ni * 16 + l15) * 64 + swz]);
#pragma unroll
            for (int mi = 0; mi < 4; mi++)
#pragma unroll
                for (int ni = 0; ni < 2; ni++)
                    acc[mi][ni] = __builtin_amdgcn_mfma_f32_16x16x32_bf16(
                        af[mi], bf[ni], acc[mi][ni], 0, 0, 0);
        }
    }

    if (OUT_MODE == 2) {
        // ---- V^T epilogue: stage 128c x 64r tile in Bs, coalesced write ----
        __syncthreads();   // all waves done reading LDS from the last tile
#pragma unroll
        for (int ni = 0; ni < 2; ni++) {
            int c = wave * 32 + ni * 16 + l15;        // local col 0..127
            float bv = bias[col0 + c];
#pragma unroll
            for (int mi = 0; mi < 4; mi++) {
                int r = mi * 16 + quad * 4;           // local row, multiple of 4
                ushort4 pk;
                pk.x = f2bf(acc[mi][ni][0] + bv);
                pk.y = f2bf(acc[mi][ni][1] + bv);
                pk.z = f2bf(acc[mi][ni][2] + bv);
                pk.w = f2bf(acc[mi][ni][3] + bv);
                *(ushort4*)(Bs + c * 64 + (r ^ ((c & 7) << 3))) = pk;  // XOR swz
            }
        }
        __syncthreads();
        // 1024 items = 128 cols x 8 row-blocks(16B); 8 consecutive lanes share c
#pragma unroll
        for (int itx = 0; itx < 4; ++itx) {
            int item = itx * 256 + tid;
            int c  = item >> 3;        // 0..127
            int rb = item & 7;         // logical 8-elem row block
            uint4v v = *(const uint4v*)(Bs + c * 64 + ((rb ^ (c & 7)) * 8));
            *(uint4v*)((unsigned short*)Cout + (size_t)(col0 + c) * BN_ + row0 + rb * 8) = v;
        }
        return;
    }

    if (OUT_MODE == 1 || OUT_MODE == 3) {
        // ---- Q/K epilogue: stage 64r x 128c tile in Bs, coalesced write ----
        __syncthreads();   // all waves done reading LDS from the last tile
#pragma unroll
        for (int ni = 0; ni < 2; ni++) {
            int c = wave * 32 + ni * 16 + l15;        // local col 0..127
            float bv = bias[col0 + c];
#pragma unroll
            for (int mi = 0; mi < 4; mi++) {
#pragma unroll
                for (int r = 0; r < 4; r++) {
                    float v = acc[mi][ni][r] + bv;
                    if (OUT_MODE == 3) v *= QSCL;
                    int row = mi * 16 + quad * 4 + r; // 0..63
                    Bs[row * 128 + (c ^ ((row & 7) << 3))] = f2bf(v);
                }
            }
        }
        __syncthreads();
        // 1024 items = 64 rows x 16 col-blocks(16B); 16 lanes = 256B/row
#pragma unroll
        for (int itx = 0; itx < 4; ++itx) {
            int item = itx * 256 + tid;
            int row = item >> 4;       // 0..63
            int cb  = item & 15;       // 16B col block
            uint4v v = *(const uint4v*)(Bs + row * 128 + ((cb ^ (row & 7)) * 8));
            *(uint4v*)((unsigned short*)Cout + (size_t)(row0 + row) * D_ + col0 + cb * 8) = v;
        }
        return;
    }

    // OUT_MODE 0: fp32 out — 16 lanes x 4B = 64B contiguous, already clean
#pragma unroll
    for (int ni = 0; ni < 2; ni++) {
        int col = col0 + wave * 32 + ni * 16 + l15;
        float bv = bias[col];
#pragma unroll
        for (int mi = 0; mi < 4; mi++) {
            int row = row0 + mi * 16 + quad * 4;
#pragma unroll
            for (int r = 0; r < 4; r++)
                ((float*)Cout)[(size_t)(row + r) * D_ + col] = acc[mi][ni][r] + bv;
        }
    }
}

// XCD-aware bijective block swizzle (T1), nwg = 8x64 = 512 per z-slice.
__device__ __forceinline__ void xcd_swz(int& bx, int& by) {
    int w = blockIdx.y * 8 + blockIdx.x;      // dispatch-flat (x fastest)
    int s = (w & 7) * 64 + (w >> 3);          // bijective, nwg=512
    bx = s & 7; by = s >> 3;
}

// Kernel 2: fused QKV projection (z selects q/k/v; q pre-scaled, v transposed)
__global__ __launch_bounds__(256, 5) void qkv_gemm(
    const unsigned short* __restrict__ xb,
    const unsigned short* __restrict__ wqb, const unsigned short* __restrict__ wkb,
    const unsigned short* __restrict__ wvb,
    const float* __restrict__ bq, const float* __restrict__ bk, const float* __restrict__ bv,
    unsigned short* __restrict__ q, unsigned short* __restrict__ k, unsigned short* __restrict__ vt)
{
    __shared__ __align__(16) unsigned short As[64 * 64];    //  8 KB
    __shared__ __align__(16) unsigned short Bs[128 * 64];   // 16 KB
    int bx, by; xcd_swz(bx, by);
    if (blockIdx.z == 0)
        gemm_body<3>(As, Bs, xb, wqb, bq, q,  bx, by);
    else if (blockIdx.z == 1)
        gemm_body<1>(As, Bs, xb, wkb, bk, k,  bx, by);
    else
        gemm_body<2>(As, Bs, xb, wvb, bv, vt, bx, by);
}

// Kernel 4: output projection, fp32 out
__global__ __launch_bounds__(256, 5) void out_gemm(
    const unsigned short* __restrict__ attn, const unsigned short* __restrict__ wob,
    const float* __restrict__ bo, float* __restrict__ out)
{
    __shared__ __align__(16) unsigned short As[64 * 64];
    __shared__ __align__(16) unsigned short Bs[128 * 64];
    int bx, by; xcd_swz(bx, by);
    gemm_body<0>(As, Bs, attn, wob, bo, out, bx, by);
}

// ---------------------------------------------------------------------------
// Kernel 3: flash attention — R9 form unchanged (setprio kept).
// ---------------------------------------------------------------------------
__global__ __launch_bounds__(256) void attn_kernel(
    const unsigned short* __restrict__ q, const unsigned short* __restrict__ k,
    const unsigned short* __restrict__ vt, unsigned short* __restrict__ o)
{
    __shared__ __align__(16) unsigned short Ks[2][64 * 64];
    __shared__ __align__(16) unsigned short Vs[2][64 * 64];

    const int tid = threadIdx.x;
    const int lane = tid & 63, wave = tid >> 6;
    const int l31 = lane & 31, kq = lane >> 5;
    const int bh = blockIdx.x;
    const int qt = blockIdx.y;
    const int b = bh >> 4, h = bh & 15;

    const unsigned short* qb = q  + (size_t)b * N_ * D_ + h * DH_;
    const unsigned short* kb = k  + (size_t)b * N_ * D_ + h * DH_;
    const unsigned short* vb = vt + (size_t)h * DH_ * BN_ + (size_t)b * N_;

    const int qrow0 = qt * 128 + wave * 32;

    short8 qf[4];
#pragma unroll
    for (int s = 0; s < 4; s++)
        qf[s] = *(const short8*)(qb + (size_t)(qrow0 + l31) * D_ + s * 16 + kq * 8);

    f32x16 oacc[2] = {};
    float lsum = 0.f;

    const int srow = lane >> 3, scb = lane & 7;

    auto stage = [&](int bi, int kv0) {
#pragma unroll
        for (int cc = 0; cc < 2; ++cc) {
            int c  = wave * 2 + cc;
            int lr = c * 8 + srow;
            int swz8 = (scb ^ (lr & 7)) * 8;
            async_load16(kb + (size_t)(kv0 + lr) * D_ + swz8, (unsigned short*)Ks[bi] + c * 512);
            async_load16(vb + (size_t)lr * BN_ + kv0 + swz8,  (unsigned short*)Vs[bi] + c * 512);
        }
    };

    stage(0, 0);

    const int NIT = N_ / 64;
    for (int it = 0; it < NIT; ++it) {
        const int cur = it & 1;
        __syncthreads();
        if (it + 1 < NIT) stage(cur ^ 1, (it + 1) * 64);

        const unsigned short* Kc = Ks[cur];
        const unsigned short* Vc = Vs[cur];

        f32x16 st[2] = {};
        __builtin_amdgcn_s_setprio(1);
#pragma unroll
        for (int s = 0; s < 4; s++) {
#pragma unroll
            for (int mb = 0; mb < 2; mb++) {
                short8 kfr = *(const short8*)((const char*)Kc +
                    (mb * 32 + l31) * 128 + (((2 * s + kq) ^ (l31 & 7)) * 16));
                st[mb] = __builtin_amdgcn_mfma_f32_32x32x16_bf16(
                    kfr, qf[s], st[mb], 0, 0, 0);
            }
        }
        __builtin_amdgcn_s_setprio(0);

#pragma unroll
        for (int mb = 0; mb < 2; mb++) {
            unsigned int pk[8];
#pragma unroll
            for (int g = 0; g < 4; g++) {
                float p0 = EXP2(st[mb][g * 4 + 0]);
                float p1 = EXP2(st[mb][g * 4 + 1]);
                float p2 = EXP2(st[mb][g * 4 + 2]);
                float p3 = EXP2(st[mb][g * 4 + 3]);
                lsum += (p0 + p1) + (p2 + p3);
                pk[2 * g + 0] = pkbf(p0, p1);
                pk[2 * g + 1] = pkbf(p2, p3);
            }
            __builtin_amdgcn_s_setprio(1);
#pragma unroll
            for (int s = 0; s < 2; s++) {
                uint4v fu;
                fu[0] = pk[4 * s + 0]; fu[1] = pk[4 * s + 1];
                fu[2] = pk[4 * s + 2]; fu[3] = pk[4 * s + 3];
                short8 pf = __builtin_bit_cast(short8, fu);
                const int blkA = 4 * mb + 2 * s;
#pragma unroll
                for (int nb = 0; nb < 2; nb++) {
                    const char* vrow = (const char*)Vc + (nb * 32 + l31) * 128;
                    uint2 vlo = *(const uint2*)(vrow + ((blkA       ^ (l31 & 7)) * 16) + kq * 8);
                    uint2 vhi = *(const uint2*)(vrow + (((blkA + 1) ^ (l31 & 7)) * 16) + kq * 8);
                    uint4v vu; vu[0] = vlo.x; vu[1] = vlo.y; vu[2] = vhi.x; vu[3] = vhi.y;
                    short8 vf = __builtin_bit_cast(short8, vu);
                    oacc[nb] = __builtin_amdgcn_mfma_f32_32x32x16_bf16(
                        pf, vf, oacc[nb], 0, 0, 0);
                }
            }
            __builtin_amdgcn_s_setprio(0);
        }
    }

    lsum += __shfl_xor(lsum, 32);
    __syncthreads();
    float* Lt = (float*)&Ks[0][0] + wave * 32;
    if (kq == 0) Lt[l31] = lsum;
    asm volatile("s_waitcnt lgkmcnt(0)" ::: "memory");

#pragma unroll
    for (int g = 0; g < 4; g++)
#pragma unroll
        for (int rr = 0; rr < 4; rr++) {
            int reg = g * 4 + rr;
            float inv = 1.f / Lt[rr + 8 * g + 4 * kq];
            int row = qrow0 + rr + 8 * g + 4 * kq;
            size_t base = ((size_t)b * N_ + row) * D_ + h * DH_;
#pragma unroll
            for (int nb = 0; nb < 2; nb++)
                o[base + nb * 32 + l31] = f2bf(oacc[nb][reg] * inv);
        }
}

// ---------------------------------------------------------------------------
extern "C" void kernel_launch(void* const* d_in, const int* in_sizes, int n_in,
                              void* d_out, int out_size, void* d_ws, size_t ws_size,
                              hipStream_t stream)
{
    const float* x  = (const float*)d_in[0];
    const float* Wq = (const float*)d_in[1];
    const float* bq = (const float*)d_in[2];
    const float* Wk = (const float*)d_in[3];
    const float* bk = (const float*)d_in[4];
    const float* Wv = (const float*)d_in[5];
    const float* bv = (const float*)d_in[6];
    const float* Wo = (const float*)d_in[7];
    const float* bo = (const float*)d_in[8];
    float* out = (float*)d_out;

    char* ws = (char*)d_ws;
    unsigned short* xb  = (unsigned short*)(ws + 0);         //  8 MB  x bf16
    unsigned short* wqb = (unsigned short*)(ws + 8388608);   //  2 MB
    unsigned short* wkb = (unsigned short*)(ws + 10485760);  //  2 MB
    unsigned short* wvb = (unsigned short*)(ws + 12582912);  //  2 MB
    unsigned short* wob = (unsigned short*)(ws + 14680064);  //  2 MB
    unsigned short* qd  = (unsigned short*)(ws + 16777216);  //  8 MB  Q (pre-scaled)
    unsigned short* kd  = (unsigned short*)(ws + 25165824);  //  8 MB
    unsigned short* vtd = (unsigned short*)(ws + 33554432);  //  8 MB  V^T [D][B*N]
    unsigned short* ad  = (unsigned short*)(ws + 41943040);  //  8 MB  attn out
    // total 48 MB

    cast_kernel<<<8192, 256, 0, stream>>>(x, Wq, Wk, Wv, Wo, xb, wqb, wkb, wvb, wob);
    qkv_gemm<<<dim3(8, 64, 3), 256, 0, stream>>>(xb, wqb, wkb, wvb, bq, bk, bv, qd, kd, vtd);
    attn_kernel<<<dim3(32, 16), 256, 0, stream>>>(qd, kd, vtd, ad);
    out_gemm<<<dim3(8, 64), 256, 0, stream>>>(ad, wob, bo, out);
}

// Round 12
// 191.231 us; speedup vs baseline: 1.6524x; 1.0189x over previous
//
#include <hip/hip_runtime.h>
#include <hip/hip_bf16.h>

// Problem constants
#define B_  2
#define N_  2048
#define D_  1024
#define H_  16
#define DH_ 64
#define BN_ (B_*N_)   // 4096 rows total

typedef __attribute__((ext_vector_type(8))) short short8;    // 8 bf16 (K=16/32 A/B frag)
typedef __attribute__((ext_vector_type(4))) float f32x4;     // 16x16 C/D frag
typedef __attribute__((ext_vector_type(16))) float f32x16;   // 32x32 C/D frag
typedef __attribute__((ext_vector_type(4))) unsigned int uint4v;

typedef __attribute__((address_space(3))) unsigned int lds_u32_t;
typedef const __attribute__((address_space(1))) unsigned int glb_u32_t;

// async global->LDS, 16B per lane; LDS dst = (wave-uniform base) + lane*16
__device__ __forceinline__ void async_load16(const unsigned short* g, unsigned short* l) {
    __builtin_amdgcn_global_load_lds((glb_u32_t*)g, (lds_u32_t*)l, 16, 0, 0);
}

__device__ __forceinline__ unsigned short f2bf(float f) {
    __hip_bfloat16 h = __float2bfloat16(f);
    return *reinterpret_cast<unsigned short*>(&h);
}

// pack bf16(a) low16 | bf16(b) high16; round-half-up + one v_perm_b32
__device__ __forceinline__ unsigned int pkbf(float a, float b) {
    unsigned int ua = __float_as_uint(a) + 0x8000u;
    unsigned int ub = __float_as_uint(b) + 0x8000u;
    return __builtin_amdgcn_perm(ub, ua, 0x07060302);
}

#if __has_builtin(__builtin_amdgcn_exp2f)
#define EXP2(x) __builtin_amdgcn_exp2f(x)
#else
#define EXP2(x) exp2f(x)
#endif

// softmax scale folded into Q projection: 1/sqrt(DH) * log2(e)
#define QSCL 0.1803368801111204f

// ---------------------------------------------------------------------------
// Kernel 1: cast fp32 -> bf16 for x, Wq, Wk, Wv, Wo (one fused launch)
// ---------------------------------------------------------------------------
__global__ __launch_bounds__(256) void cast_kernel(
    const float* __restrict__ x,  const float* __restrict__ wq,
    const float* __restrict__ wk, const float* __restrict__ wv,
    const float* __restrict__ wo,
    unsigned short* __restrict__ xb,  unsigned short* __restrict__ wqb,
    unsigned short* __restrict__ wkb, unsigned short* __restrict__ wvb,
    unsigned short* __restrict__ wob)
{
    const size_t NX = (size_t)BN_ * D_;   // 4194304
    const size_t NW = (size_t)D_ * D_;    // 1048576 (pow2)
    size_t i = ((size_t)blockIdx.x * 256 + threadIdx.x) * 4;
    const float* src; unsigned short* dst; size_t off;
    if (i < NX) { src = x; dst = xb; off = i; }
    else {
        size_t j = (i - NX) >> 20;          // which W
        off = (i - NX) & (NW - 1);
        src = (j == 0) ? wq : (j == 1) ? wk : (j == 2) ? wv : wo;
        dst = (j == 0) ? wqb : (j == 1) ? wkb : (j == 2) ? wvb : wob;
    }
    float4 v = *(const float4*)(src + off);
    ushort4 o;
    o.x = f2bf(v.x); o.y = f2bf(v.y); o.z = f2bf(v.z); o.w = f2bf(v.w);
    *(ushort4*)(dst + off) = o;
}

// ---------------------------------------------------------------------------
// Kernel 2 (R12): FUSED QKV — one block computes Q, K, V for its 64x128 tile.
// Rationale: R8/R9/R11 = three different structures, qkv pinned ~60us with
// nothing saturated (R10 direct: Mfma 16.5 / VALU 11 / Occ 41) -> per-k-step
// serial chain (stage + barrier-drain amortized over only ~620cyc of MFMA)
// is the surviving bottleneck model. Fusing z-slices triples MFMA per k-step
// (48 vs 16) for +8 staging loads, and reads the x-tile ONCE instead of 3x.
// LDS 8 + 3x16 = 56 KB -> exactly 2 blocks/CU, grid 512 = zero tail.
// L2 REGION SWIZZLE: with 3 W's live, old per-XCD footprint (6MB W) would
// thrash 4MB L2. New map: XCD k owns a 2-bx x 32-by region -> W 1.5MB +
// A 2MB <= 4MB, W L2-resident across all 64 blocks of the XCD.
// Epilogues = the three R11-verified ones (Q/K coalesced row-major, V^T
// transposed), merged: one barrier pair, disjoint LDS regions.
// ---------------------------------------------------------------------------
__global__ __launch_bounds__(256, 2) void qkv_fused(
    const unsigned short* __restrict__ xb,
    const unsigned short* __restrict__ wqb, const unsigned short* __restrict__ wkb,
    const unsigned short* __restrict__ wvb,
    const float* __restrict__ bq, const float* __restrict__ bk, const float* __restrict__ bv,
    unsigned short* __restrict__ q, unsigned short* __restrict__ k, unsigned short* __restrict__ vt)
{
    __shared__ __align__(16) unsigned short As[64 * 64];     //  8 KB  x tile
    __shared__ __align__(16) unsigned short Bq[128 * 64];    // 16 KB  Wq tile / Q stage
    __shared__ __align__(16) unsigned short Bk[128 * 64];    // 16 KB  Wk tile / K stage
    __shared__ __align__(16) unsigned short Bv[128 * 64];    // 16 KB  Wv tile / V^T stage

    const int tid  = threadIdx.x;
    const int lane = tid & 63;
    const int wave = tid >> 6;
    const int l15 = lane & 15, quad = lane >> 4;

    // region swizzle: xcd = blockIdx.x (d%8 with gridDim.x=8), j = blockIdx.y
    const int p  = blockIdx.x & 3, hh = blockIdx.x >> 2;
    const int bx = p * 2 + (blockIdx.y & 1);
    const int by = hh * 32 + (blockIdx.y >> 1);
    const int row0 = by * 64, col0 = bx * 128;

    const int srow = lane >> 3, scb = lane & 7;

    f32x4 aq[4][2] = {}, ak[4][2] = {}, av[4][2] = {};

    for (int k0 = 0; k0 < D_; k0 += 64) {
        __syncthreads();
#pragma unroll
        for (int cc = 0; cc < 2; ++cc) {          // A: 8 chunks
            int c  = wave * 2 + cc;
            int lr = c * 8 + srow;                // 0..63
            int gcol = k0 + ((scb ^ (lr & 7)) * 8);
            async_load16(xb + (size_t)(row0 + lr) * D_ + gcol, As + c * 512);
        }
#pragma unroll
        for (int cc = 0; cc < 4; ++cc) {          // each W: 16 chunks
            int c  = wave * 4 + cc;
            int lr = c * 8 + srow;                // 0..127
            int gcol = k0 + ((scb ^ (lr & 7)) * 8);
            size_t off = (size_t)(col0 + lr) * D_ + gcol;
            async_load16(wqb + off, Bq + c * 512);
            async_load16(wkb + off, Bk + c * 512);
            async_load16(wvb + off, Bv + c * 512);
        }
        __syncthreads();

#pragma unroll
        for (int kf = 0; kf < 2; ++kf) {
            const int swz = ((kf * 4 + quad) ^ (l15 & 7)) * 8;
            short8 af[4];
#pragma unroll
            for (int mi = 0; mi < 4; mi++)
                af[mi] = *(const short8*)(&As[(mi * 16 + l15) * 64 + swz]);
#pragma unroll
            for (int ni = 0; ni < 2; ni++) {
                const int boff = (wave * 32 + ni * 16 + l15) * 64 + swz;
                short8 fq = *(const short8*)(&Bq[boff]);
                short8 fk = *(const short8*)(&Bk[boff]);
                short8 fv = *(const short8*)(&Bv[boff]);
#pragma unroll
                for (int mi = 0; mi < 4; mi++) {
                    aq[mi][ni] = __builtin_amdgcn_mfma_f32_16x16x32_bf16(af[mi], fq, aq[mi][ni], 0, 0, 0);
                    ak[mi][ni] = __builtin_amdgcn_mfma_f32_16x16x32_bf16(af[mi], fk, ak[mi][ni], 0, 0, 0);
                    av[mi][ni] = __builtin_amdgcn_mfma_f32_16x16x32_bf16(af[mi], fv, av[mi][ni], 0, 0, 0);
                }
            }
        }
    }

    // ---- merged epilogues: scatter to disjoint LDS regions, then coop write
    __syncthreads();   // all waves done reading staging LDS
#pragma unroll
    for (int ni = 0; ni < 2; ni++) {
        int c = wave * 32 + ni * 16 + l15;        // local col 0..127
        float biq = bq[col0 + c], bik = bk[col0 + c], biv = bv[col0 + c];
#pragma unroll
        for (int mi = 0; mi < 4; mi++) {
            int r4 = mi * 16 + quad * 4;          // local row, multiple of 4
            // V^T: [128c][64r] XOR-swizzled (R11-verified scheme)
            ushort4 pv;
            pv.x = f2bf(av[mi][ni][0] + biv);
            pv.y = f2bf(av[mi][ni][1] + biv);
            pv.z = f2bf(av[mi][ni][2] + biv);
            pv.w = f2bf(av[mi][ni][3] + biv);
            *(ushort4*)(Bv + c * 64 + (r4 ^ ((c & 7) << 3))) = pv;
            // Q (pre-scaled) and K: [64r][128c] XOR-swizzled (R11-verified)
#pragma unroll
            for (int r = 0; r < 4; r++) {
                int row = r4 + r;
                int sc  = c ^ ((row & 7) << 3);
                Bq[row * 128 + sc] = f2bf((aq[mi][ni][r] + biq) * QSCL);
                Bk[row * 128 + sc] = f2bf(ak[mi][ni][r] + bik);
            }
        }
    }
    __syncthreads();
#pragma unroll
    for (int itx = 0; itx < 4; ++itx) {
        int item = itx * 256 + tid;
        // Q/K: 64 rows x 16 col-blocks(16B); 16 lanes = 256B contiguous/row
        int row = item >> 4, cb = item & 15;
        uint4v vq = *(const uint4v*)(Bq + row * 128 + ((cb ^ (row & 7)) * 8));
        *(uint4v*)(q + (size_t)(row0 + row) * D_ + col0 + cb * 8) = vq;
        uint4v vk = *(const uint4v*)(Bk + row * 128 + ((cb ^ (row & 7)) * 8));
        *(uint4v*)(k + (size_t)(row0 + row) * D_ + col0 + cb * 8) = vk;
        // V^T: 128 cols x 8 row-blocks(16B); 8 lanes = 128B contiguous/col
        int c = item >> 3, rb = item & 7;
        uint4v vv = *(const uint4v*)(Bv + c * 64 + ((rb ^ (c & 7)) * 8));
        *(uint4v*)(vt + (size_t)(col0 + c) * BN_ + row0 + rb * 8) = vv;
    }
}

// ---------------------------------------------------------------------------
// GEMM body (out_gemm only now): 64x128 tile, 4 waves x acc[4][2], 24 KB LDS.
// ---------------------------------------------------------------------------
template<int OUT_MODE>
__device__ __forceinline__ void gemm_body(
    unsigned short* __restrict__ As, unsigned short* __restrict__ Bs,
    const unsigned short* __restrict__ A, const unsigned short* __restrict__ W,
    const float* __restrict__ bias, void* __restrict__ Cout, int bx, int by)
{
    constexpr int K = D_;
    const int tid  = threadIdx.x;
    const int lane = tid & 63;
    const int wave = tid >> 6;
    const int l15 = lane & 15, quad = lane >> 4;

    f32x4 acc[4][2] = {};
    const int row0 = by * 64, col0 = bx * 128;

    const int srow = lane >> 3;   // row within 1KB chunk (8 rows x 128B)
    const int scb  = lane & 7;    // 16B block within row

    for (int k0 = 0; k0 < K; k0 += 64) {
        __syncthreads();
#pragma unroll
        for (int cc = 0; cc < 2; ++cc) {
            int c  = wave * 2 + cc;
            int lr = c * 8 + srow;
            int gcol = k0 + ((scb ^ (lr & 7)) * 8);
            async_load16(A + (size_t)(row0 + lr) * K + gcol, As + c * 512);
        }
#pragma unroll
        for (int cc = 0; cc < 4; ++cc) {
            int c  = wave * 4 + cc;
            int lr = c * 8 + srow;
            int gcol = k0 + ((scb ^ (lr & 7)) * 8);
            async_load16(W + (size_t)(col0 + lr) * K + gcol, Bs + c * 512);
        }
        __syncthreads();

#pragma unroll
        for (int kf = 0; kf < 2; ++kf) {
            const int swz = ((kf * 4 + quad) ^ (l15 & 7)) * 8;
            short8 af[4], bf[2];
#pragma unroll
            for (int mi = 0; mi < 4; mi++)
                af[mi] = *(const short8*)(&As[(mi * 16 + l15) * 64 + swz]);
#pragma unroll
            for (int ni = 0; ni < 2; ni++)
                bf[ni] = *(const short8*)(&Bs[(wave * 32 + ni * 16 + l15) * 64 + swz]);
#pragma unroll
            for (int mi = 0; mi < 4; mi++)
#pragma unroll
                for (int ni = 0; ni < 2; ni++)
                    acc[mi][ni] = __builtin_amdgcn_mfma_f32_16x16x32_bf16(
                        af[mi], bf[ni], acc[mi][ni], 0, 0, 0);
        }
    }

    // OUT_MODE 0: fp32 out — 16 lanes x 4B = 64B contiguous, clean
#pragma unroll
    for (int ni = 0; ni < 2; ni++) {
        int col = col0 + wave * 32 + ni * 16 + l15;
        float bvv = bias[col];
#pragma unroll
        for (int mi = 0; mi < 4; mi++) {
            int row = row0 + mi * 16 + quad * 4;
#pragma unroll
            for (int r = 0; r < 4; r++)
                ((float*)Cout)[(size_t)(row + r) * D_ + col] = acc[mi][ni][r] + bvv;
        }
    }
}

// XCD-aware bijective block swizzle (T1), nwg = 8x64 = 512 (out_gemm: one W,
// 2MB + 1MB A per XCD fits L2 with the original 8-by-panel mapping).
__device__ __forceinline__ void xcd_swz(int& bx, int& by) {
    int w = blockIdx.y * 8 + blockIdx.x;      // dispatch-flat (x fastest)
    int s = (w & 7) * 64 + (w >> 3);          // bijective, nwg=512
    bx = s & 7; by = s >> 3;
}

// Kernel 4: output projection, fp32 out
__global__ __launch_bounds__(256, 5) void out_gemm(
    const unsigned short* __restrict__ attn, const unsigned short* __restrict__ wob,
    const float* __restrict__ bo, float* __restrict__ out)
{
    __shared__ __align__(16) unsigned short As[64 * 64];
    __shared__ __align__(16) unsigned short Bs[128 * 64];
    int bx, by; xcd_swz(bx, by);
    gemm_body<0>(As, Bs, attn, wob, bo, out, bx, by);
}

// ---------------------------------------------------------------------------
// Kernel 3: flash attention — unchanged (noise anchor, ~63-70us band).
// ---------------------------------------------------------------------------
__global__ __launch_bounds__(256) void attn_kernel(
    const unsigned short* __restrict__ q, const unsigned short* __restrict__ k,
    const unsigned short* __restrict__ vt, unsigned short* __restrict__ o)
{
    __shared__ __align__(16) unsigned short Ks[2][64 * 64];
    __shared__ __align__(16) unsigned short Vs[2][64 * 64];

    const int tid = threadIdx.x;
    const int lane = tid & 63, wave = tid >> 6;
    const int l31 = lane & 31, kq = lane >> 5;
    const int bh = blockIdx.x;
    const int qt = blockIdx.y;
    const int b = bh >> 4, h = bh & 15;

    const unsigned short* qb = q  + (size_t)b * N_ * D_ + h * DH_;
    const unsigned short* kb = k  + (size_t)b * N_ * D_ + h * DH_;
    const unsigned short* vb = vt + (size_t)h * DH_ * BN_ + (size_t)b * N_;

    const int qrow0 = qt * 128 + wave * 32;

    short8 qf[4];
#pragma unroll
    for (int s = 0; s < 4; s++)
        qf[s] = *(const short8*)(qb + (size_t)(qrow0 + l31) * D_ + s * 16 + kq * 8);

    f32x16 oacc[2] = {};
    float lsum = 0.f;

    const int srow = lane >> 3, scb = lane & 7;

    auto stage = [&](int bi, int kv0) {
#pragma unroll
        for (int cc = 0; cc < 2; ++cc) {
            int c  = wave * 2 + cc;
            int lr = c * 8 + srow;
            int swz8 = (scb ^ (lr & 7)) * 8;
            async_load16(kb + (size_t)(kv0 + lr) * D_ + swz8, (unsigned short*)Ks[bi] + c * 512);
            async_load16(vb + (size_t)lr * BN_ + kv0 + swz8,  (unsigned short*)Vs[bi] + c * 512);
        }
    };

    stage(0, 0);

    const int NIT = N_ / 64;
    for (int it = 0; it < NIT; ++it) {
        const int cur = it & 1;
        __syncthreads();
        if (it + 1 < NIT) stage(cur ^ 1, (it + 1) * 64);

        const unsigned short* Kc = Ks[cur];
        const unsigned short* Vc = Vs[cur];

        f32x16 st[2] = {};
        __builtin_amdgcn_s_setprio(1);
#pragma unroll
        for (int s = 0; s < 4; s++) {
#pragma unroll
            for (int mb = 0; mb < 2; mb++) {
                short8 kfr = *(const short8*)((const char*)Kc +
                    (mb * 32 + l31) * 128 + (((2 * s + kq) ^ (l31 & 7)) * 16));
                st[mb] = __builtin_amdgcn_mfma_f32_32x32x16_bf16(
                    kfr, qf[s], st[mb], 0, 0, 0);
            }
        }
        __builtin_amdgcn_s_setprio(0);

#pragma unroll
        for (int mb = 0; mb < 2; mb++) {
            unsigned int pk[8];
#pragma unroll
            for (int g = 0; g < 4; g++) {
                float p0 = EXP2(st[mb][g * 4 + 0]);
                float p1 = EXP2(st[mb][g * 4 + 1]);
                float p2 = EXP2(st[mb][g * 4 + 2]);
                float p3 = EXP2(st[mb][g * 4 + 3]);
                lsum += (p0 + p1) + (p2 + p3);
                pk[2 * g + 0] = pkbf(p0, p1);
                pk[2 * g + 1] = pkbf(p2, p3);
            }
            __builtin_amdgcn_s_setprio(1);
#pragma unroll
            for (int s = 0; s < 2; s++) {
                uint4v fu;
                fu[0] = pk[4 * s + 0]; fu[1] = pk[4 * s + 1];
                fu[2] = pk[4 * s + 2]; fu[3] = pk[4 * s + 3];
                short8 pf = __builtin_bit_cast(short8, fu);
                const int blkA = 4 * mb + 2 * s;
#pragma unroll
                for (int nb = 0; nb < 2; nb++) {
                    const char* vrow = (const char*)Vc + (nb * 32 + l31) * 128;
                    uint2 vlo = *(const uint2*)(vrow + ((blkA       ^ (l31 & 7)) * 16) + kq * 8);
                    uint2 vhi = *(const uint2*)(vrow + (((blkA + 1) ^ (l31 & 7)) * 16) + kq * 8);
                    uint4v vu; vu[0] = vlo.x; vu[1] = vlo.y; vu[2] = vhi.x; vu[3] = vhi.y;
                    short8 vf = __builtin_bit_cast(short8, vu);
                    oacc[nb] = __builtin_amdgcn_mfma_f32_32x32x16_bf16(
                        pf, vf, oacc[nb], 0, 0, 0);
                }
            }
            __builtin_amdgcn_s_setprio(0);
        }
    }

    lsum += __shfl_xor(lsum, 32);
    __syncthreads();
    float* Lt = (float*)&Ks[0][0] + wave * 32;
    if (kq == 0) Lt[l31] = lsum;
    asm volatile("s_waitcnt lgkmcnt(0)" ::: "memory");

#pragma unroll
    for (int g = 0; g < 4; g++)
#pragma unroll
        for (int rr = 0; rr < 4; rr++) {
            int reg = g * 4 + rr;
            float inv = 1.f / Lt[rr + 8 * g + 4 * kq];
            int row = qrow0 + rr + 8 * g + 4 * kq;
            size_t base = ((size_t)b * N_ + row) * D_ + h * DH_;
#pragma unroll
            for (int nb = 0; nb < 2; nb++)
                o[base + nb * 32 + l31] = f2bf(oacc[nb][reg] * inv);
        }
}

// ---------------------------------------------------------------------------
extern "C" void kernel_launch(void* const* d_in, const int* in_sizes, int n_in,
                              void* d_out, int out_size, void* d_ws, size_t ws_size,
                              hipStream_t stream)
{
    const float* x  = (const float*)d_in[0];
    const float* Wq = (const float*)d_in[1];
    const float* bq = (const float*)d_in[2];
    const float* Wk = (const float*)d_in[3];
    const float* bk = (const float*)d_in[4];
    const float* Wv = (const float*)d_in[5];
    const float* bv = (const float*)d_in[6];
    const float* Wo = (const float*)d_in[7];
    const float* bo = (const float*)d_in[8];
    float* out = (float*)d_out;

    char* ws = (char*)d_ws;
    unsigned short* xb  = (unsigned short*)(ws + 0);         //  8 MB  x bf16
    unsigned short* wqb = (unsigned short*)(ws + 8388608);   //  2 MB
    unsigned short* wkb = (unsigned short*)(ws + 10485760);  //  2 MB
    unsigned short* wvb = (unsigned short*)(ws + 12582912);  //  2 MB
    unsigned short* wob = (unsigned short*)(ws + 14680064);  //  2 MB
    unsigned short* qd  = (unsigned short*)(ws + 16777216);  //  8 MB  Q (pre-scaled)
    unsigned short* kd  = (unsigned short*)(ws + 25165824);  //  8 MB
    unsigned short* vtd = (unsigned short*)(ws + 33554432);  //  8 MB  V^T [D][B*N]
    unsigned short* ad  = (unsigned short*)(ws + 41943040);  //  8 MB  attn out
    // total 48 MB

    cast_kernel<<<8192, 256, 0, stream>>>(x, Wq, Wk, Wv, Wo, xb, wqb, wkb, wvb, wob);
    qkv_fused<<<dim3(8, 64), 256, 0, stream>>>(xb, wqb, wkb, wvb, bq, bk, bv, qd, kd, vtd);
    attn_kernel<<<dim3(32, 16), 256, 0, stream>>>(qd, kd, vtd, ad);
    out_gemm<<<dim3(8, 64), 256, 0, stream>>>(ad, wob, bo, out);
}

// Round 13
// 184.128 us; speedup vs baseline: 1.7162x; 1.0386x over previous
//
#include <hip/hip_runtime.h>
#include <hip/hip_bf16.h>

// Problem constants
#define B_  2
#define N_  2048
#define D_  1024
#define H_  16
#define DH_ 64
#define BN_ (B_*N_)   // 4096 rows total

typedef __attribute__((ext_vector_type(8))) short short8;    // 8 bf16 (K=16/32 A/B frag)
typedef __attribute__((ext_vector_type(4))) float f32x4;     // 16x16 C/D frag
typedef __attribute__((ext_vector_type(16))) float f32x16;   // 32x32 C/D frag
typedef __attribute__((ext_vector_type(4))) unsigned int uint4v;

typedef __attribute__((address_space(3))) unsigned int lds_u32_t;
typedef const __attribute__((address_space(1))) unsigned int glb_u32_t;

// async global->LDS, 16B per lane; LDS dst = (wave-uniform base) + lane*16
__device__ __forceinline__ void async_load16(const unsigned short* g, unsigned short* l) {
    __builtin_amdgcn_global_load_lds((glb_u32_t*)g, (lds_u32_t*)l, 16, 0, 0);
}

__device__ __forceinline__ unsigned short f2bf(float f) {
    __hip_bfloat16 h = __float2bfloat16(f);
    return *reinterpret_cast<unsigned short*>(&h);
}

// pack bf16(a) low16 | bf16(b) high16; round-half-up + one v_perm_b32
__device__ __forceinline__ unsigned int pkbf(float a, float b) {
    unsigned int ua = __float_as_uint(a) + 0x8000u;
    unsigned int ub = __float_as_uint(b) + 0x8000u;
    return __builtin_amdgcn_perm(ub, ua, 0x07060302);
}

#if __has_builtin(__builtin_amdgcn_exp2f)
#define EXP2(x) __builtin_amdgcn_exp2f(x)
#else
#define EXP2(x) exp2f(x)
#endif

// softmax scale folded into Q projection: 1/sqrt(DH) * log2(e)
#define QSCL 0.1803368801111204f

// ---------------------------------------------------------------------------
// Kernel 1: cast fp32 -> bf16 for x, Wq, Wk, Wv, Wo (one fused launch)
// ---------------------------------------------------------------------------
__global__ __launch_bounds__(256) void cast_kernel(
    const float* __restrict__ x,  const float* __restrict__ wq,
    const float* __restrict__ wk, const float* __restrict__ wv,
    const float* __restrict__ wo,
    unsigned short* __restrict__ xb,  unsigned short* __restrict__ wqb,
    unsigned short* __restrict__ wkb, unsigned short* __restrict__ wvb,
    unsigned short* __restrict__ wob)
{
    const size_t NX = (size_t)BN_ * D_;   // 4194304
    const size_t NW = (size_t)D_ * D_;    // 1048576 (pow2)
    size_t i = ((size_t)blockIdx.x * 256 + threadIdx.x) * 4;
    const float* src; unsigned short* dst; size_t off;
    if (i < NX) { src = x; dst = xb; off = i; }
    else {
        size_t j = (i - NX) >> 20;          // which W
        off = (i - NX) & (NW - 1);
        src = (j == 0) ? wq : (j == 1) ? wk : (j == 2) ? wv : wo;
        dst = (j == 0) ? wqb : (j == 1) ? wkb : (j == 2) ? wvb : wob;
    }
    float4 v = *(const float4*)(src + off);
    ushort4 o;
    o.x = f2bf(v.x); o.y = f2bf(v.y); o.z = f2bf(v.z); o.w = f2bf(v.w);
    *(ushort4*)(dst + off) = o;
}

// ---------------------------------------------------------------------------
// Kernel 2 (R12-verified): FUSED QKV — one block computes Q, K, V for its
// 64x128 tile. LDS 56 KB -> 2 blocks/CU; L2 region swizzle (2bx x 32by per
// XCD). Epilogues: Q/K coalesced row-major, V^T transposed (all verified).
// ---------------------------------------------------------------------------
__global__ __launch_bounds__(256, 2) void qkv_fused(
    const unsigned short* __restrict__ xb,
    const unsigned short* __restrict__ wqb, const unsigned short* __restrict__ wkb,
    const unsigned short* __restrict__ wvb,
    const float* __restrict__ bq, const float* __restrict__ bk, const float* __restrict__ bv,
    unsigned short* __restrict__ q, unsigned short* __restrict__ k, unsigned short* __restrict__ vt)
{
    __shared__ __align__(16) unsigned short As[64 * 64];     //  8 KB  x tile
    __shared__ __align__(16) unsigned short Bq[128 * 64];    // 16 KB  Wq tile / Q stage
    __shared__ __align__(16) unsigned short Bk[128 * 64];    // 16 KB  Wk tile / K stage
    __shared__ __align__(16) unsigned short Bv[128 * 64];    // 16 KB  Wv tile / V^T stage

    const int tid  = threadIdx.x;
    const int lane = tid & 63;
    const int wave = tid >> 6;
    const int l15 = lane & 15, quad = lane >> 4;

    // region swizzle: xcd = blockIdx.x (d%8 with gridDim.x=8), j = blockIdx.y
    const int p  = blockIdx.x & 3, hh = blockIdx.x >> 2;
    const int bx = p * 2 + (blockIdx.y & 1);
    const int by = hh * 32 + (blockIdx.y >> 1);
    const int row0 = by * 64, col0 = bx * 128;

    const int srow = lane >> 3, scb = lane & 7;

    f32x4 aq[4][2] = {}, ak[4][2] = {}, av[4][2] = {};

    for (int k0 = 0; k0 < D_; k0 += 64) {
        __syncthreads();
#pragma unroll
        for (int cc = 0; cc < 2; ++cc) {          // A: 8 chunks
            int c  = wave * 2 + cc;
            int lr = c * 8 + srow;                // 0..63
            int gcol = k0 + ((scb ^ (lr & 7)) * 8);
            async_load16(xb + (size_t)(row0 + lr) * D_ + gcol, As + c * 512);
        }
#pragma unroll
        for (int cc = 0; cc < 4; ++cc) {          // each W: 16 chunks
            int c  = wave * 4 + cc;
            int lr = c * 8 + srow;                // 0..127
            int gcol = k0 + ((scb ^ (lr & 7)) * 8);
            size_t off = (size_t)(col0 + lr) * D_ + gcol;
            async_load16(wqb + off, Bq + c * 512);
            async_load16(wkb + off, Bk + c * 512);
            async_load16(wvb + off, Bv + c * 512);
        }
        __syncthreads();

#pragma unroll
        for (int kf = 0; kf < 2; ++kf) {
            const int swz = ((kf * 4 + quad) ^ (l15 & 7)) * 8;
            short8 af[4];
#pragma unroll
            for (int mi = 0; mi < 4; mi++)
                af[mi] = *(const short8*)(&As[(mi * 16 + l15) * 64 + swz]);
#pragma unroll
            for (int ni = 0; ni < 2; ni++) {
                const int boff = (wave * 32 + ni * 16 + l15) * 64 + swz;
                short8 fq = *(const short8*)(&Bq[boff]);
                short8 fk = *(const short8*)(&Bk[boff]);
                short8 fv = *(const short8*)(&Bv[boff]);
#pragma unroll
                for (int mi = 0; mi < 4; mi++) {
                    aq[mi][ni] = __builtin_amdgcn_mfma_f32_16x16x32_bf16(af[mi], fq, aq[mi][ni], 0, 0, 0);
                    ak[mi][ni] = __builtin_amdgcn_mfma_f32_16x16x32_bf16(af[mi], fk, ak[mi][ni], 0, 0, 0);
                    av[mi][ni] = __builtin_amdgcn_mfma_f32_16x16x32_bf16(af[mi], fv, av[mi][ni], 0, 0, 0);
                }
            }
        }
    }

    // ---- merged epilogues: scatter to disjoint LDS regions, then coop write
    __syncthreads();   // all waves done reading staging LDS
#pragma unroll
    for (int ni = 0; ni < 2; ni++) {
        int c = wave * 32 + ni * 16 + l15;        // local col 0..127
        float biq = bq[col0 + c], bik = bk[col0 + c], biv = bv[col0 + c];
#pragma unroll
        for (int mi = 0; mi < 4; mi++) {
            int r4 = mi * 16 + quad * 4;          // local row, multiple of 4
            ushort4 pv;
            pv.x = f2bf(av[mi][ni][0] + biv);
            pv.y = f2bf(av[mi][ni][1] + biv);
            pv.z = f2bf(av[mi][ni][2] + biv);
            pv.w = f2bf(av[mi][ni][3] + biv);
            *(ushort4*)(Bv + c * 64 + (r4 ^ ((c & 7) << 3))) = pv;
#pragma unroll
            for (int r = 0; r < 4; r++) {
                int row = r4 + r;
                int sc  = c ^ ((row & 7) << 3);
                Bq[row * 128 + sc] = f2bf((aq[mi][ni][r] + biq) * QSCL);
                Bk[row * 128 + sc] = f2bf(ak[mi][ni][r] + bik);
            }
        }
    }
    __syncthreads();
#pragma unroll
    for (int itx = 0; itx < 4; ++itx) {
        int item = itx * 256 + tid;
        int row = item >> 4, cb = item & 15;
        uint4v vq = *(const uint4v*)(Bq + row * 128 + ((cb ^ (row & 7)) * 8));
        *(uint4v*)(q + (size_t)(row0 + row) * D_ + col0 + cb * 8) = vq;
        uint4v vk = *(const uint4v*)(Bk + row * 128 + ((cb ^ (row & 7)) * 8));
        *(uint4v*)(k + (size_t)(row0 + row) * D_ + col0 + cb * 8) = vk;
        int c = item >> 3, rb = item & 7;
        uint4v vv = *(const uint4v*)(Bv + c * 64 + ((rb ^ (c & 7)) * 8));
        *(uint4v*)(vt + (size_t)(col0 + c) * BN_ + row0 + rb * 8) = vv;
    }
}

// ---------------------------------------------------------------------------
// GEMM body (out_gemm only): 64x128 tile, 4 waves x acc[4][2], 24 KB LDS.
// ---------------------------------------------------------------------------
template<int OUT_MODE>
__device__ __forceinline__ void gemm_body(
    unsigned short* __restrict__ As, unsigned short* __restrict__ Bs,
    const unsigned short* __restrict__ A, const unsigned short* __restrict__ W,
    const float* __restrict__ bias, void* __restrict__ Cout, int bx, int by)
{
    constexpr int K = D_;
    const int tid  = threadIdx.x;
    const int lane = tid & 63;
    const int wave = tid >> 6;
    const int l15 = lane & 15, quad = lane >> 4;

    f32x4 acc[4][2] = {};
    const int row0 = by * 64, col0 = bx * 128;

    const int srow = lane >> 3;
    const int scb  = lane & 7;

    for (int k0 = 0; k0 < K; k0 += 64) {
        __syncthreads();
#pragma unroll
        for (int cc = 0; cc < 2; ++cc) {
            int c  = wave * 2 + cc;
            int lr = c * 8 + srow;
            int gcol = k0 + ((scb ^ (lr & 7)) * 8);
            async_load16(A + (size_t)(row0 + lr) * K + gcol, As + c * 512);
        }
#pragma unroll
        for (int cc = 0; cc < 4; ++cc) {
            int c  = wave * 4 + cc;
            int lr = c * 8 + srow;
            int gcol = k0 + ((scb ^ (lr & 7)) * 8);
            async_load16(W + (size_t)(col0 + lr) * K + gcol, Bs + c * 512);
        }
        __syncthreads();

#pragma unroll
        for (int kf = 0; kf < 2; ++kf) {
            const int swz = ((kf * 4 + quad) ^ (l15 & 7)) * 8;
            short8 af[4], bf[2];
#pragma unroll
            for (int mi = 0; mi < 4; mi++)
                af[mi] = *(const short8*)(&As[(mi * 16 + l15) * 64 + swz]);
#pragma unroll
            for (int ni = 0; ni < 2; ni++)
                bf[ni] = *(const short8*)(&Bs[(wave * 32 + ni * 16 + l15) * 64 + swz]);
#pragma unroll
            for (int mi = 0; mi < 4; mi++)
#pragma unroll
                for (int ni = 0; ni < 2; ni++)
                    acc[mi][ni] = __builtin_amdgcn_mfma_f32_16x16x32_bf16(
                        af[mi], bf[ni], acc[mi][ni], 0, 0, 0);
        }
    }

    // OUT_MODE 0: fp32 out — 16 lanes x 4B = 64B contiguous, clean
#pragma unroll
    for (int ni = 0; ni < 2; ni++) {
        int col = col0 + wave * 32 + ni * 16 + l15;
        float bvv = bias[col];
#pragma unroll
        for (int mi = 0; mi < 4; mi++) {
            int row = row0 + mi * 16 + quad * 4;
#pragma unroll
            for (int r = 0; r < 4; r++)
                ((float*)Cout)[(size_t)(row + r) * D_ + col] = acc[mi][ni][r] + bvv;
        }
    }
}

// XCD-aware bijective block swizzle (T1), nwg = 8x64 = 512.
__device__ __forceinline__ void xcd_swz(int& bx, int& by) {
    int w = blockIdx.y * 8 + blockIdx.x;      // dispatch-flat (x fastest)
    int s = (w & 7) * 64 + (w >> 3);          // bijective, nwg=512
    bx = s & 7; by = s >> 3;
}

// Kernel 4: output projection, fp32 out
__global__ __launch_bounds__(256, 5) void out_gemm(
    const unsigned short* __restrict__ attn, const unsigned short* __restrict__ wob,
    const float* __restrict__ bo, float* __restrict__ out)
{
    __shared__ __align__(16) unsigned short As[64 * 64];
    __shared__ __align__(16) unsigned short Bs[128 * 64];
    int bx, by; xcd_swz(bx, by);
    gemm_body<0>(As, Bs, attn, wob, bo, out, bx, by);
}

// ---------------------------------------------------------------------------
// Kernel 3 (R13): flash attention, IN-BLOCK KV-SPLIT — 8 waves/block (512
// threads), grid unchanged. Waves 0-3 process kv tiles 0..15 (buffer 0),
// waves 4-7 process tiles 16..31 (buffer 1) — the dbuf LDS already holds
// exactly 2 tiles, so LDS stays 32 KB -> 2 blocks/CU, but 16 waves/CU =
// 4 waves/SIMD (was 2). Cycle ledger (R12): 1906 cyc/iter-SIMD of which
// VALU 1067 + MFMA 420 -> ~440 stall; doubling TLP makes VALU the binding
// pipe -> wall ~16 steps x ~2200 cyc. Per-wave inner math byte-identical
// to the verified kernel; pair merges oacc+lsum IN-BLOCK via LDS (no global
// partials, no combine kernel — the R4-R6 lesson). Merge layout: element-
// quad-major, 16B/lane stride = 2-way banks = free (m136). Prefetch dropped
// (would need 4 buffers -> 1 block/CU); exposed load latency covered by
// doubled TLP + 2-block de-phasing.
// ---------------------------------------------------------------------------
__global__ __launch_bounds__(512, 4) void attn_kernel(
    const unsigned short* __restrict__ q, const unsigned short* __restrict__ k,
    const unsigned short* __restrict__ vt, unsigned short* __restrict__ o)
{
    __shared__ __align__(16) unsigned short Ks[2][64 * 64];   // 16 KB (tileA | tileB)
    __shared__ __align__(16) unsigned short Vs[2][64 * 64];   // 16 KB
    __shared__ float Ls[4][32];                               // 512 B lsum merge

    const int tid = threadIdx.x;
    const int lane = tid & 63, wave = tid >> 6;   // wave 0..7
    const int l31 = lane & 31, kq = lane >> 5;
    const int wlow = wave & 3;                    // row-group 0..3
    const int half = wave >> 2;                   // kv half 0/1
    const int bh = blockIdx.x;
    const int qt = blockIdx.y;
    const int b = bh >> 4, h = bh & 15;

    const unsigned short* qb = q  + (size_t)b * N_ * D_ + h * DH_;
    const unsigned short* kb = k  + (size_t)b * N_ * D_ + h * DH_;
    const unsigned short* vb = vt + (size_t)h * DH_ * BN_ + (size_t)b * N_;

    const int qrow0 = qt * 128 + wlow * 32;

    short8 qf[4];
#pragma unroll
    for (int s = 0; s < 4; s++)
        qf[s] = *(const short8*)(qb + (size_t)(qrow0 + l31) * D_ + s * 16 + kq * 8);

    f32x16 oacc[2] = {};
    float lsum = 0.f;

    const int srow = lane >> 3, scb = lane & 7;
    const int kvoff = half * (N_ / 2);            // 0 or 1024

    const int NIT = 16;                            // 16 tiles per half
    for (int it = 0; it < NIT; ++it) {
        // each wave stages its OWN half's tile into its buffer
        {
            const int kv0 = kvoff + it * 64;
#pragma unroll
            for (int cc = 0; cc < 2; ++cc) {
                int c  = wlow * 2 + cc;           // 0..7
                int lr = c * 8 + srow;
                int swz8 = (scb ^ (lr & 7)) * 8;
                async_load16(kb + (size_t)(kv0 + lr) * D_ + swz8, (unsigned short*)Ks[half] + c * 512);
                async_load16(vb + (size_t)lr * BN_ + kv0 + swz8,  (unsigned short*)Vs[half] + c * 512);
            }
        }
        __syncthreads();   // drains vmcnt -> both buffers ready

        const unsigned short* Kc = Ks[half];
        const unsigned short* Vc = Vs[half];

        f32x16 st[2] = {};
        __builtin_amdgcn_s_setprio(1);
#pragma unroll
        for (int s = 0; s < 4; s++) {
#pragma unroll
            for (int mb = 0; mb < 2; mb++) {
                short8 kfr = *(const short8*)((const char*)Kc +
                    (mb * 32 + l31) * 128 + (((2 * s + kq) ^ (l31 & 7)) * 16));
                st[mb] = __builtin_amdgcn_mfma_f32_32x32x16_bf16(
                    kfr, qf[s], st[mb], 0, 0, 0);
            }
        }
        __builtin_amdgcn_s_setprio(0);

#pragma unroll
        for (int mb = 0; mb < 2; mb++) {
            unsigned int pk[8];
#pragma unroll
            for (int g = 0; g < 4; g++) {
                float p0 = EXP2(st[mb][g * 4 + 0]);
                float p1 = EXP2(st[mb][g * 4 + 1]);
                float p2 = EXP2(st[mb][g * 4 + 2]);
                float p3 = EXP2(st[mb][g * 4 + 3]);
                lsum += (p0 + p1) + (p2 + p3);
                pk[2 * g + 0] = pkbf(p0, p1);
                pk[2 * g + 1] = pkbf(p2, p3);
            }
            __builtin_amdgcn_s_setprio(1);
#pragma unroll
            for (int s = 0; s < 2; s++) {
                uint4v fu;
                fu[0] = pk[4 * s + 0]; fu[1] = pk[4 * s + 1];
                fu[2] = pk[4 * s + 2]; fu[3] = pk[4 * s + 3];
                short8 pf = __builtin_bit_cast(short8, fu);
                const int blkA = 4 * mb + 2 * s;
#pragma unroll
                for (int nb = 0; nb < 2; nb++) {
                    const char* vrow = (const char*)Vc + (nb * 32 + l31) * 128;
                    uint2 vlo = *(const uint2*)(vrow + ((blkA       ^ (l31 & 7)) * 16) + kq * 8);
                    uint2 vhi = *(const uint2*)(vrow + (((blkA + 1) ^ (l31 & 7)) * 16) + kq * 8);
                    uint4v vu; vu[0] = vlo.x; vu[1] = vlo.y; vu[2] = vhi.x; vu[3] = vhi.y;
                    short8 vf = __builtin_bit_cast(short8, vu);
                    oacc[nb] = __builtin_amdgcn_mfma_f32_32x32x16_bf16(
                        pf, vf, oacc[nb], 0, 0, 0);
                }
            }
            __builtin_amdgcn_s_setprio(0);
        }
        __syncthreads();   // all reads of this tile done -> buffers reusable
    }

    // ---- in-block pair merge: wave w (lower) + wave w+4 (upper) ----
    lsum += __shfl_xor(lsum, 32);   // full row-sum of this wave's kv half

    // merge region for pair idx: idx 0,1 -> Ks halves; idx 2,3 -> Vs halves
    const int idx = wave & 3;
    float* mrg = ((idx & 2) ? (float*)Vs : (float*)Ks) + (idx & 1) * 2048;

    if (wave >= 4) {
        // upper: publish oacc (element-quad-major, 16B/lane stride) + lsum
#pragma unroll
        for (int q8 = 0; q8 < 8; ++q8) {
            int nb = q8 >> 2, j = (q8 & 3) * 4;
            f32x4 c;
            c[0] = oacc[nb][j + 0]; c[1] = oacc[nb][j + 1];
            c[2] = oacc[nb][j + 2]; c[3] = oacc[nb][j + 3];
            *(f32x4*)(mrg + (q8 * 64 + lane) * 4) = c;
        }
        if (kq == 0) Ls[wave - 4][l31] = lsum;
    }
    __syncthreads();
    if (wave < 4) {
        // lower: accumulate partner's oacc + lsum
#pragma unroll
        for (int q8 = 0; q8 < 8; ++q8) {
            int nb = q8 >> 2, j = (q8 & 3) * 4;
            f32x4 r = *(const f32x4*)(mrg + (q8 * 64 + lane) * 4);
            oacc[nb][j + 0] += r[0]; oacc[nb][j + 1] += r[1];
            oacc[nb][j + 2] += r[2]; oacc[nb][j + 3] += r[3];
        }
        lsum += Ls[wave][l31];
    }
    __syncthreads();   // merge reads done before Lt overwrites Ks

    if (wave < 4) {
        float* Lt = (float*)&Ks[0][0] + wave * 32;
        if (kq == 0) Lt[l31] = lsum;
        asm volatile("s_waitcnt lgkmcnt(0)" ::: "memory");

#pragma unroll
        for (int g = 0; g < 4; g++)
#pragma unroll
            for (int rr = 0; rr < 4; rr++) {
                int reg = g * 4 + rr;
                float inv = 1.f / Lt[rr + 8 * g + 4 * kq];
                int row = qrow0 + rr + 8 * g + 4 * kq;
                size_t base = ((size_t)b * N_ + row) * D_ + h * DH_;
#pragma unroll
                for (int nb = 0; nb < 2; nb++)
                    o[base + nb * 32 + l31] = f2bf(oacc[nb][reg] * inv);
            }
    }
}

// ---------------------------------------------------------------------------
extern "C" void kernel_launch(void* const* d_in, const int* in_sizes, int n_in,
                              void* d_out, int out_size, void* d_ws, size_t ws_size,
                              hipStream_t stream)
{
    const float* x  = (const float*)d_in[0];
    const float* Wq = (const float*)d_in[1];
    const float* bq = (const float*)d_in[2];
    const float* Wk = (const float*)d_in[3];
    const float* bk = (const float*)d_in[4];
    const float* Wv = (const float*)d_in[5];
    const float* bv = (const float*)d_in[6];
    const float* Wo = (const float*)d_in[7];
    const float* bo = (const float*)d_in[8];
    float* out = (float*)d_out;

    char* ws = (char*)d_ws;
    unsigned short* xb  = (unsigned short*)(ws + 0);         //  8 MB  x bf16
    unsigned short* wqb = (unsigned short*)(ws + 8388608);   //  2 MB
    unsigned short* wkb = (unsigned short*)(ws + 10485760);  //  2 MB
    unsigned short* wvb = (unsigned short*)(ws + 12582912);  //  2 MB
    unsigned short* wob = (unsigned short*)(ws + 14680064);  //  2 MB
    unsigned short* qd  = (unsigned short*)(ws + 16777216);  //  8 MB  Q (pre-scaled)
    unsigned short* kd  = (unsigned short*)(ws + 25165824);  //  8 MB
    unsigned short* vtd = (unsigned short*)(ws + 33554432);  //  8 MB  V^T [D][B*N]
    unsigned short* ad  = (unsigned short*)(ws + 41943040);  //  8 MB  attn out
    // total 48 MB

    cast_kernel<<<8192, 256, 0, stream>>>(x, Wq, Wk, Wv, Wo, xb, wqb, wkb, wvb, wob);
    qkv_fused<<<dim3(8, 64), 256, 0, stream>>>(xb, wqb, wkb, wvb, bq, bk, bv, qd, kd, vtd);
    attn_kernel<<<dim3(32, 16), 512, 0, stream>>>(qd, kd, vtd, ad);
    out_gemm<<<dim3(8, 64), 256, 0, stream>>>(ad, wob, bo, out);
}

// Round 14
// 182.697 us; speedup vs baseline: 1.7296x; 1.0078x over previous
//
#include <hip/hip_runtime.h>
#include <hip/hip_bf16.h>

// Problem constants
#define B_  2
#define N_  2048
#define D_  1024
#define H_  16
#define DH_ 64
#define BN_ (B_*N_)   // 4096 rows total

typedef __attribute__((ext_vector_type(8))) short short8;    // 8 bf16 (K=16/32 A/B frag)
typedef __attribute__((ext_vector_type(4))) float f32x4;     // 16x16 C/D frag
typedef __attribute__((ext_vector_type(16))) float f32x16;   // 32x32 C/D frag
typedef __attribute__((ext_vector_type(4))) unsigned int uint4v;

typedef __attribute__((address_space(3))) unsigned int lds_u32_t;
typedef const __attribute__((address_space(1))) unsigned int glb_u32_t;

// async global->LDS, 16B per lane; LDS dst = (wave-uniform base) + lane*16
__device__ __forceinline__ void async_load16(const unsigned short* g, unsigned short* l) {
    __builtin_amdgcn_global_load_lds((glb_u32_t*)g, (lds_u32_t*)l, 16, 0, 0);
}

__device__ __forceinline__ unsigned short f2bf(float f) {
    __hip_bfloat16 h = __float2bfloat16(f);
    return *reinterpret_cast<unsigned short*>(&h);
}

// pack bf16(a) low16 | bf16(b) high16; round-half-up + one v_perm_b32
__device__ __forceinline__ unsigned int pkbf(float a, float b) {
    unsigned int ua = __float_as_uint(a) + 0x8000u;
    unsigned int ub = __float_as_uint(b) + 0x8000u;
    return __builtin_amdgcn_perm(ub, ua, 0x07060302);
}

#if __has_builtin(__builtin_amdgcn_exp2f)
#define EXP2(x) __builtin_amdgcn_exp2f(x)
#else
#define EXP2(x) exp2f(x)
#endif

// softmax scale folded into Q projection: 1/sqrt(DH) * log2(e)
#define QSCL 0.1803368801111204f

// ---------------------------------------------------------------------------
// Kernel 1: cast fp32 -> bf16 for x, Wq, Wk, Wv, Wo (one fused launch)
// ---------------------------------------------------------------------------
__global__ __launch_bounds__(256) void cast_kernel(
    const float* __restrict__ x,  const float* __restrict__ wq,
    const float* __restrict__ wk, const float* __restrict__ wv,
    const float* __restrict__ wo,
    unsigned short* __restrict__ xb,  unsigned short* __restrict__ wqb,
    unsigned short* __restrict__ wkb, unsigned short* __restrict__ wvb,
    unsigned short* __restrict__ wob)
{
    const size_t NX = (size_t)BN_ * D_;   // 4194304
    const size_t NW = (size_t)D_ * D_;    // 1048576 (pow2)
    size_t i = ((size_t)blockIdx.x * 256 + threadIdx.x) * 4;
    const float* src; unsigned short* dst; size_t off;
    if (i < NX) { src = x; dst = xb; off = i; }
    else {
        size_t j = (i - NX) >> 20;          // which W
        off = (i - NX) & (NW - 1);
        src = (j == 0) ? wq : (j == 1) ? wk : (j == 2) ? wv : wo;
        dst = (j == 0) ? wqb : (j == 1) ? wkb : (j == 2) ? wvb : wob;
    }
    float4 v = *(const float4*)(src + off);
    ushort4 o;
    o.x = f2bf(v.x); o.y = f2bf(v.y); o.z = f2bf(v.z); o.w = f2bf(v.w);
    *(ushort4*)(dst + off) = o;
}

// ---------------------------------------------------------------------------
// Kernel 2 (R12-verified): FUSED QKV — one block computes Q, K, V for its
// 64x128 tile. LDS 56 KB -> 2 blocks/CU; L2 region swizzle (2bx x 32by per
// XCD). Epilogues: Q/K coalesced row-major, V^T transposed (all verified).
// ---------------------------------------------------------------------------
__global__ __launch_bounds__(256, 2) void qkv_fused(
    const unsigned short* __restrict__ xb,
    const unsigned short* __restrict__ wqb, const unsigned short* __restrict__ wkb,
    const unsigned short* __restrict__ wvb,
    const float* __restrict__ bq, const float* __restrict__ bk, const float* __restrict__ bv,
    unsigned short* __restrict__ q, unsigned short* __restrict__ k, unsigned short* __restrict__ vt)
{
    __shared__ __align__(16) unsigned short As[64 * 64];     //  8 KB  x tile
    __shared__ __align__(16) unsigned short Bq[128 * 64];    // 16 KB  Wq tile / Q stage
    __shared__ __align__(16) unsigned short Bk[128 * 64];    // 16 KB  Wk tile / K stage
    __shared__ __align__(16) unsigned short Bv[128 * 64];    // 16 KB  Wv tile / V^T stage

    const int tid  = threadIdx.x;
    const int lane = tid & 63;
    const int wave = tid >> 6;
    const int l15 = lane & 15, quad = lane >> 4;

    // region swizzle: xcd = blockIdx.x (d%8 with gridDim.x=8), j = blockIdx.y
    const int p  = blockIdx.x & 3, hh = blockIdx.x >> 2;
    const int bx = p * 2 + (blockIdx.y & 1);
    const int by = hh * 32 + (blockIdx.y >> 1);
    const int row0 = by * 64, col0 = bx * 128;

    const int srow = lane >> 3, scb = lane & 7;

    f32x4 aq[4][2] = {}, ak[4][2] = {}, av[4][2] = {};

    for (int k0 = 0; k0 < D_; k0 += 64) {
        __syncthreads();
#pragma unroll
        for (int cc = 0; cc < 2; ++cc) {          // A: 8 chunks
            int c  = wave * 2 + cc;
            int lr = c * 8 + srow;                // 0..63
            int gcol = k0 + ((scb ^ (lr & 7)) * 8);
            async_load16(xb + (size_t)(row0 + lr) * D_ + gcol, As + c * 512);
        }
#pragma unroll
        for (int cc = 0; cc < 4; ++cc) {          // each W: 16 chunks
            int c  = wave * 4 + cc;
            int lr = c * 8 + srow;                // 0..127
            int gcol = k0 + ((scb ^ (lr & 7)) * 8);
            size_t off = (size_t)(col0 + lr) * D_ + gcol;
            async_load16(wqb + off, Bq + c * 512);
            async_load16(wkb + off, Bk + c * 512);
            async_load16(wvb + off, Bv + c * 512);
        }
        __syncthreads();

#pragma unroll
        for (int kf = 0; kf < 2; ++kf) {
            const int swz = ((kf * 4 + quad) ^ (l15 & 7)) * 8;
            short8 af[4];
#pragma unroll
            for (int mi = 0; mi < 4; mi++)
                af[mi] = *(const short8*)(&As[(mi * 16 + l15) * 64 + swz]);
#pragma unroll
            for (int ni = 0; ni < 2; ni++) {
                const int boff = (wave * 32 + ni * 16 + l15) * 64 + swz;
                short8 fq = *(const short8*)(&Bq[boff]);
                short8 fk = *(const short8*)(&Bk[boff]);
                short8 fv = *(const short8*)(&Bv[boff]);
#pragma unroll
                for (int mi = 0; mi < 4; mi++) {
                    aq[mi][ni] = __builtin_amdgcn_mfma_f32_16x16x32_bf16(af[mi], fq, aq[mi][ni], 0, 0, 0);
                    ak[mi][ni] = __builtin_amdgcn_mfma_f32_16x16x32_bf16(af[mi], fk, ak[mi][ni], 0, 0, 0);
                    av[mi][ni] = __builtin_amdgcn_mfma_f32_16x16x32_bf16(af[mi], fv, av[mi][ni], 0, 0, 0);
                }
            }
        }
    }

    // ---- merged epilogues: scatter to disjoint LDS regions, then coop write
    __syncthreads();   // all waves done reading staging LDS
#pragma unroll
    for (int ni = 0; ni < 2; ni++) {
        int c = wave * 32 + ni * 16 + l15;        // local col 0..127
        float biq = bq[col0 + c], bik = bk[col0 + c], biv = bv[col0 + c];
#pragma unroll
        for (int mi = 0; mi < 4; mi++) {
            int r4 = mi * 16 + quad * 4;          // local row, multiple of 4
            ushort4 pv;
            pv.x = f2bf(av[mi][ni][0] + biv);
            pv.y = f2bf(av[mi][ni][1] + biv);
            pv.z = f2bf(av[mi][ni][2] + biv);
            pv.w = f2bf(av[mi][ni][3] + biv);
            *(ushort4*)(Bv + c * 64 + (r4 ^ ((c & 7) << 3))) = pv;
#pragma unroll
            for (int r = 0; r < 4; r++) {
                int row = r4 + r;
                int sc  = c ^ ((row & 7) << 3);
                Bq[row * 128 + sc] = f2bf((aq[mi][ni][r] + biq) * QSCL);
                Bk[row * 128 + sc] = f2bf(ak[mi][ni][r] + bik);
            }
        }
    }
    __syncthreads();
#pragma unroll
    for (int itx = 0; itx < 4; ++itx) {
        int item = itx * 256 + tid;
        int row = item >> 4, cb = item & 15;
        uint4v vq = *(const uint4v*)(Bq + row * 128 + ((cb ^ (row & 7)) * 8));
        *(uint4v*)(q + (size_t)(row0 + row) * D_ + col0 + cb * 8) = vq;
        uint4v vk = *(const uint4v*)(Bk + row * 128 + ((cb ^ (row & 7)) * 8));
        *(uint4v*)(k + (size_t)(row0 + row) * D_ + col0 + cb * 8) = vk;
        int c = item >> 3, rb = item & 7;
        uint4v vv = *(const uint4v*)(Bv + c * 64 + ((rb ^ (c & 7)) * 8));
        *(uint4v*)(vt + (size_t)(col0 + c) * BN_ + row0 + rb * 8) = vv;
    }
}

// ---------------------------------------------------------------------------
// GEMM body (out_gemm only): 64x128 tile, 4 waves x acc[4][2], 24 KB LDS.
// ---------------------------------------------------------------------------
template<int OUT_MODE>
__device__ __forceinline__ void gemm_body(
    unsigned short* __restrict__ As, unsigned short* __restrict__ Bs,
    const unsigned short* __restrict__ A, const unsigned short* __restrict__ W,
    const float* __restrict__ bias, void* __restrict__ Cout, int bx, int by)
{
    constexpr int K = D_;
    const int tid  = threadIdx.x;
    const int lane = tid & 63;
    const int wave = tid >> 6;
    const int l15 = lane & 15, quad = lane >> 4;

    f32x4 acc[4][2] = {};
    const int row0 = by * 64, col0 = bx * 128;

    const int srow = lane >> 3;
    const int scb  = lane & 7;

    for (int k0 = 0; k0 < K; k0 += 64) {
        __syncthreads();
#pragma unroll
        for (int cc = 0; cc < 2; ++cc) {
            int c  = wave * 2 + cc;
            int lr = c * 8 + srow;
            int gcol = k0 + ((scb ^ (lr & 7)) * 8);
            async_load16(A + (size_t)(row0 + lr) * K + gcol, As + c * 512);
        }
#pragma unroll
        for (int cc = 0; cc < 4; ++cc) {
            int c  = wave * 4 + cc;
            int lr = c * 8 + srow;
            int gcol = k0 + ((scb ^ (lr & 7)) * 8);
            async_load16(W + (size_t)(col0 + lr) * K + gcol, Bs + c * 512);
        }
        __syncthreads();

#pragma unroll
        for (int kf = 0; kf < 2; ++kf) {
            const int swz = ((kf * 4 + quad) ^ (l15 & 7)) * 8;
            short8 af[4], bf[2];
#pragma unroll
            for (int mi = 0; mi < 4; mi++)
                af[mi] = *(const short8*)(&As[(mi * 16 + l15) * 64 + swz]);
#pragma unroll
            for (int ni = 0; ni < 2; ni++)
                bf[ni] = *(const short8*)(&Bs[(wave * 32 + ni * 16 + l15) * 64 + swz]);
#pragma unroll
            for (int mi = 0; mi < 4; mi++)
#pragma unroll
                for (int ni = 0; ni < 2; ni++)
                    acc[mi][ni] = __builtin_amdgcn_mfma_f32_16x16x32_bf16(
                        af[mi], bf[ni], acc[mi][ni], 0, 0, 0);
        }
    }

    // OUT_MODE 0: fp32 out — 16 lanes x 4B = 64B contiguous, clean
#pragma unroll
    for (int ni = 0; ni < 2; ni++) {
        int col = col0 + wave * 32 + ni * 16 + l15;
        float bvv = bias[col];
#pragma unroll
        for (int mi = 0; mi < 4; mi++) {
            int row = row0 + mi * 16 + quad * 4;
#pragma unroll
            for (int r = 0; r < 4; r++)
                ((float*)Cout)[(size_t)(row + r) * D_ + col] = acc[mi][ni][r] + bvv;
        }
    }
}

// XCD-aware bijective block swizzle (T1), nwg = 8x64 = 512.
__device__ __forceinline__ void xcd_swz(int& bx, int& by) {
    int w = blockIdx.y * 8 + blockIdx.x;      // dispatch-flat (x fastest)
    int s = (w & 7) * 64 + (w >> 3);          // bijective, nwg=512
    bx = s & 7; by = s >> 3;
}

// Kernel 4: output projection, fp32 out
__global__ __launch_bounds__(256, 5) void out_gemm(
    const unsigned short* __restrict__ attn, const unsigned short* __restrict__ wob,
    const float* __restrict__ bo, float* __restrict__ out)
{
    __shared__ __align__(16) unsigned short As[64 * 64];
    __shared__ __align__(16) unsigned short Bs[128 * 64];
    int bx, by; xcd_swz(bx, by);
    gemm_body<0>(As, Bs, attn, wob, bo, out, bx, by);
}

// ---------------------------------------------------------------------------
// Kernel 3 (R14): flash attention, in-block KV-split (R13-verified) + RESTORED
// per-half double-buffer prefetch. R13 post-mortem: dropping prefetch exposed
// ~300-500 cyc load latency per iter (stage -> immediate barrier drain);
// VALUBusy FELL to 45% instead of rising. LDS budget allows both: 2 halves x
// 2 bufs x (8K K + 8K V) = 64 KB + 0.5 KB merge -> still 2 blocks/CU at 512
// threads (129 of 160 KB). Loop reverts to the R12-verified one-barrier
// pattern: syncthreads -> stage(cur^1, it+1) -> compute(cur). Compute and
// merge are byte-identical to R13 (merge scratch fits in the larger Ks/Vs
// at the same offsets).
// ---------------------------------------------------------------------------
__global__ __launch_bounds__(512, 4) void attn_kernel(
    const unsigned short* __restrict__ q, const unsigned short* __restrict__ k,
    const unsigned short* __restrict__ vt, unsigned short* __restrict__ o)
{
    __shared__ __align__(16) unsigned short Ks[2][2][64 * 64];   // [half][buf] 32 KB
    __shared__ __align__(16) unsigned short Vs[2][2][64 * 64];   // 32 KB
    __shared__ float Ls[4][32];                                  // 512 B lsum merge

    const int tid = threadIdx.x;
    const int lane = tid & 63, wave = tid >> 6;   // wave 0..7
    const int l31 = lane & 31, kq = lane >> 5;
    const int wlow = wave & 3;                    // row-group 0..3
    const int half = wave >> 2;                   // kv half 0/1
    const int bh = blockIdx.x;
    const int qt = blockIdx.y;
    const int b = bh >> 4, h = bh & 15;

    const unsigned short* qb = q  + (size_t)b * N_ * D_ + h * DH_;
    const unsigned short* kb = k  + (size_t)b * N_ * D_ + h * DH_;
    const unsigned short* vb = vt + (size_t)h * DH_ * BN_ + (size_t)b * N_;

    const int qrow0 = qt * 128 + wlow * 32;

    short8 qf[4];
#pragma unroll
    for (int s = 0; s < 4; s++)
        qf[s] = *(const short8*)(qb + (size_t)(qrow0 + l31) * D_ + s * 16 + kq * 8);

    f32x16 oacc[2] = {};
    float lsum = 0.f;

    const int srow = lane >> 3, scb = lane & 7;
    const int kvoff = half * (N_ / 2);            // 0 or 1024

    // stage tile (kvoff + it*64) of this wave's half into buffer bi
    auto stage = [&](int bi, int it) {
        const int kv0 = kvoff + it * 64;
#pragma unroll
        for (int cc = 0; cc < 2; ++cc) {
            int c  = wlow * 2 + cc;               // 0..7
            int lr = c * 8 + srow;
            int swz8 = (scb ^ (lr & 7)) * 8;
            async_load16(kb + (size_t)(kv0 + lr) * D_ + swz8,
                         (unsigned short*)Ks[half][bi] + c * 512);
            async_load16(vb + (size_t)lr * BN_ + kv0 + swz8,
                         (unsigned short*)Vs[half][bi] + c * 512);
        }
    };

    stage(0, 0);   // prologue

    const int NIT = 16;                            // 16 tiles per half
    for (int it = 0; it < NIT; ++it) {
        const int cur = it & 1;
        __syncthreads();   // drains vmcnt -> buf[cur] ready; buf[cur^1] free
        if (it + 1 < NIT) stage(cur ^ 1, it + 1);  // prefetch next tile

        const unsigned short* Kc = Ks[half][cur];
        const unsigned short* Vc = Vs[half][cur];

        f32x16 st[2] = {};
        __builtin_amdgcn_s_setprio(1);
#pragma unroll
        for (int s = 0; s < 4; s++) {
#pragma unroll
            for (int mb = 0; mb < 2; mb++) {
                short8 kfr = *(const short8*)((const char*)Kc +
                    (mb * 32 + l31) * 128 + (((2 * s + kq) ^ (l31 & 7)) * 16));
                st[mb] = __builtin_amdgcn_mfma_f32_32x32x16_bf16(
                    kfr, qf[s], st[mb], 0, 0, 0);
            }
        }
        __builtin_amdgcn_s_setprio(0);

#pragma unroll
        for (int mb = 0; mb < 2; mb++) {
            unsigned int pk[8];
#pragma unroll
            for (int g = 0; g < 4; g++) {
                float p0 = EXP2(st[mb][g * 4 + 0]);
                float p1 = EXP2(st[mb][g * 4 + 1]);
                float p2 = EXP2(st[mb][g * 4 + 2]);
                float p3 = EXP2(st[mb][g * 4 + 3]);
                lsum += (p0 + p1) + (p2 + p3);
                pk[2 * g + 0] = pkbf(p0, p1);
                pk[2 * g + 1] = pkbf(p2, p3);
            }
            __builtin_amdgcn_s_setprio(1);
#pragma unroll
            for (int s = 0; s < 2; s++) {
                uint4v fu;
                fu[0] = pk[4 * s + 0]; fu[1] = pk[4 * s + 1];
                fu[2] = pk[4 * s + 2]; fu[3] = pk[4 * s + 3];
                short8 pf = __builtin_bit_cast(short8, fu);
                const int blkA = 4 * mb + 2 * s;
#pragma unroll
                for (int nb = 0; nb < 2; nb++) {
                    const char* vrow = (const char*)Vc + (nb * 32 + l31) * 128;
                    uint2 vlo = *(const uint2*)(vrow + ((blkA       ^ (l31 & 7)) * 16) + kq * 8);
                    uint2 vhi = *(const uint2*)(vrow + (((blkA + 1) ^ (l31 & 7)) * 16) + kq * 8);
                    uint4v vu; vu[0] = vlo.x; vu[1] = vlo.y; vu[2] = vhi.x; vu[3] = vhi.y;
                    short8 vf = __builtin_bit_cast(short8, vu);
                    oacc[nb] = __builtin_amdgcn_mfma_f32_32x32x16_bf16(
                        pf, vf, oacc[nb], 0, 0, 0);
                }
            }
            __builtin_amdgcn_s_setprio(0);
        }
    }

    // ---- in-block pair merge: wave w (lower) + wave w+4 (upper) ----
    __syncthreads();                // all tile reads done -> Ks/Vs reusable
    lsum += __shfl_xor(lsum, 32);   // full row-sum of this wave's kv half

    // merge region for pair idx: idx 0,1 -> Ks; idx 2,3 -> Vs (8 KB each)
    const int idx = wave & 3;
    float* mrg = ((idx & 2) ? (float*)Vs : (float*)Ks) + (idx & 1) * 2048;

    if (wave >= 4) {
        // upper: publish oacc (element-quad-major, 16B/lane stride) + lsum
#pragma unroll
        for (int q8 = 0; q8 < 8; ++q8) {
            int nb = q8 >> 2, j = (q8 & 3) * 4;
            f32x4 c;
            c[0] = oacc[nb][j + 0]; c[1] = oacc[nb][j + 1];
            c[2] = oacc[nb][j + 2]; c[3] = oacc[nb][j + 3];
            *(f32x4*)(mrg + (q8 * 64 + lane) * 4) = c;
        }
        if (kq == 0) Ls[wave - 4][l31] = lsum;
    }
    __syncthreads();
    if (wave < 4) {
        // lower: accumulate partner's oacc + lsum
#pragma unroll
        for (int q8 = 0; q8 < 8; ++q8) {
            int nb = q8 >> 2, j = (q8 & 3) * 4;
            f32x4 r = *(const f32x4*)(mrg + (q8 * 64 + lane) * 4);
            oacc[nb][j + 0] += r[0]; oacc[nb][j + 1] += r[1];
            oacc[nb][j + 2] += r[2]; oacc[nb][j + 3] += r[3];
        }
        lsum += Ls[wave][l31];
    }
    __syncthreads();   // merge reads done before Lt overwrites Ks

    if (wave < 4) {
        float* Lt = (float*)&Ks[0][0][0] + wave * 32;
        if (kq == 0) Lt[l31] = lsum;
        asm volatile("s_waitcnt lgkmcnt(0)" ::: "memory");

#pragma unroll
        for (int g = 0; g < 4; g++)
#pragma unroll
            for (int rr = 0; rr < 4; rr++) {
                int reg = g * 4 + rr;
                float inv = 1.f / Lt[rr + 8 * g + 4 * kq];
                int row = qrow0 + rr + 8 * g + 4 * kq;
                size_t base = ((size_t)b * N_ + row) * D_ + h * DH_;
#pragma unroll
                for (int nb = 0; nb < 2; nb++)
                    o[base + nb * 32 + l31] = f2bf(oacc[nb][reg] * inv);
            }
    }
}

// ---------------------------------------------------------------------------
extern "C" void kernel_launch(void* const* d_in, const int* in_sizes, int n_in,
                              void* d_out, int out_size, void* d_ws, size_t ws_size,
                              hipStream_t stream)
{
    const float* x  = (const float*)d_in[0];
    const float* Wq = (const float*)d_in[1];
    const float* bq = (const float*)d_in[2];
    const float* Wk = (const float*)d_in[3];
    const float* bk = (const float*)d_in[4];
    const float* Wv = (const float*)d_in[5];
    const float* bv = (const float*)d_in[6];
    const float* Wo = (const float*)d_in[7];
    const float* bo = (const float*)d_in[8];
    float* out = (float*)d_out;

    char* ws = (char*)d_ws;
    unsigned short* xb  = (unsigned short*)(ws + 0);         //  8 MB  x bf16
    unsigned short* wqb = (unsigned short*)(ws + 8388608);   //  2 MB
    unsigned short* wkb = (unsigned short*)(ws + 10485760);  //  2 MB
    unsigned short* wvb = (unsigned short*)(ws + 12582912);  //  2 MB
    unsigned short* wob = (unsigned short*)(ws + 14680064);  //  2 MB
    unsigned short* qd  = (unsigned short*)(ws + 16777216);  //  8 MB  Q (pre-scaled)
    unsigned short* kd  = (unsigned short*)(ws + 25165824);  //  8 MB
    unsigned short* vtd = (unsigned short*)(ws + 33554432);  //  8 MB  V^T [D][B*N]
    unsigned short* ad  = (unsigned short*)(ws + 41943040);  //  8 MB  attn out
    // total 48 MB

    cast_kernel<<<8192, 256, 0, stream>>>(x, Wq, Wk, Wv, Wo, xb, wqb, wkb, wvb, wob);
    qkv_fused<<<dim3(8, 64), 256, 0, stream>>>(xb, wqb, wkb, wvb, bq, bk, bv, qd, kd, vtd);
    attn_kernel<<<dim3(32, 16), 512, 0, stream>>>(qd, kd, vtd, ad);
    out_gemm<<<dim3(8, 64), 256, 0, stream>>>(ad, wob, bo, out);
}